// Round 5
// baseline (192.674 us; speedup 1.0000x reference)
//
#include <hip/hip_runtime.h>

typedef unsigned short u16;
typedef unsigned int   u32;

using bf16x8 = __attribute__((ext_vector_type(8))) __bf16;
using f32x4  = __attribute__((ext_vector_type(4))) float;
using f32x16 = __attribute__((ext_vector_type(16))) float;
using u32x4  = __attribute__((ext_vector_type(4))) u32;

#define DEV static __device__ __forceinline__
#define GP(p) (const __attribute__((address_space(1))) void*)(p)
#define LP(p) (__attribute__((address_space(3))) void*)(p)
// fused counted-wait + barrier (T4)
#define WAITB(N) asm volatile("s_waitcnt vmcnt(" N ")\n\ts_barrier" ::: "memory")
// counted VMEM wait for reg-staged loads; sched_barrier pins register-only consumers (rule #18)
#define WAITVM(N) do{ asm volatile("s_waitcnt vmcnt(" N ")" ::: "memory"); \
                      __builtin_amdgcn_sched_barrier(0); }while(0)
// end-of-step: drain LDS ops then barrier
#define LGKMB asm volatile("s_waitcnt lgkmcnt(0)\n\ts_barrier" ::: "memory")

DEV u16 f2bf(float f){                      // RNE float->bf16
  u32 u = __builtin_bit_cast(u32, f);
  u32 r = u + 0x7fffu + ((u>>16)&1u);
  return (u16)(r>>16);
}
DEV float bcf(u32 x){ return __builtin_bit_cast(float, x); }
DEV bf16x8 as_bf(uint4 v){ return __builtin_bit_cast(bf16x8, v); }
DEV u32 cvt_pk(float lo, float hi){
  u32 r;
  asm("v_cvt_pk_bf16_f32 %0, %1, %2" : "=v"(r) : "v"(lo), "v"(hi));
  return r;
}
DEV void plswap(u32 &a, u32 &b){
  auto r = __builtin_amdgcn_permlane32_swap((int)a, (int)b, false, false);
  a = (u32)r[0]; b = (u32)r[1];
}
DEV float fexp2(float x){ float r; asm("v_exp_f32 %0, %1" : "=v"(r) : "v"(x)); return r; }
DEV float max3f(float a, float b, float c){
  float r; asm("v_max3_f32 %0, %1, %2, %3" : "=v"(r) : "v"(a), "v"(b), "v"(c)); return r;
}
DEV float fractf_(float x){ float r; asm("v_fract_f32 %0, %1" : "=v"(r) : "v"(x)); return r; }
DEV float sinrev(float f){ float r; asm("v_sin_f32 %0, %1" : "=v"(r) : "v"(f)); return r; }
DEV float cosrev(float f){ float r; asm("v_cos_f32 %0, %1" : "=v"(r) : "v"(f)); return r; }

// problem constants
constexpr int CB = 4, CL = 2048, CE = 1024, CH = 16, CD = 64;
constexpr int CM = CB*CL;           // 8192 rows
constexpr float LOG2E  = 1.44269504088896f;
constexpr float NEGBIG = -1.44269504e9f;    // -1e9 * log2e (exp2 domain)
constexpr float INV2PI = 0.15915494309189535f;

// ---------------- mask dtype detection ----------------
__global__ void detect_mask_kernel(const void* __restrict__ mask, int* __restrict__ flag){
  __shared__ int a_gt1, a_badf, a_oddnz, a_evennz;
  if (threadIdx.x==0){ a_gt1=0; a_badf=0; a_oddnz=0; a_evennz=0; }
  __syncthreads();
  const u32* w = (const u32*)mask;
  int gt1=0, badf=0, oddnz=0, evennz=0;
  for (int i=threadIdx.x; i<2048; i+=256){
    u32 v = w[i];
    if (v > 1u) gt1 = 1;
    if (v != 0u && v != 0x3f800000u) badf = 1;
    if (v != 0u){ if (i & 1) oddnz = 1; else evennz = 1; }
  }
  if (gt1) atomicOr(&a_gt1,1);
  if (badf) atomicOr(&a_badf,1);
  if (oddnz) atomicOr(&a_oddnz,1);
  if (evennz) atomicOr(&a_evennz,1);
  __syncthreads();
  if (threadIdx.x==0){
    int mode;
    if (!a_gt1)           mode = (!a_oddnz && a_evennz) ? 3 : 0;
    else if (!a_badf)     mode = 1;
    else                  mode = 2;
    flag[0] = mode;
  }
}

__global__ void convert_mask_kernel(const void* __restrict__ mask, const int* __restrict__ flag,
                                    float* __restrict__ maskf){
  int i = blockIdx.x*blockDim.x + threadIdx.x;   // B*L
  if (i >= CB*CL) return;
  int mode = flag[0];
  int v;
  if      (mode==0) v = ((const int*)mask)[i] != 0;
  else if (mode==1) v = ((const float*)mask)[i] != 0.f;
  else if (mode==3) v = ((const int*)mask)[2*i] != 0;
  else              v = ((const unsigned char*)mask)[i] != 0;
  maskf[i] = v ? NEGBIG : 0.f;
}

// ---------------- QKV projection GEMM, fp32 sources, fused cast-in-staging ----------------
// 256x128 tile, 8 waves, BK=64, ring-2 LDS + double reg sets, WRITE-LATE step (T14):
//   step t: issue global_load_dwordx4 for tile t+2 (12 loads, set t&1),
//           COMP(t) from buf[t&1]  (covers the in-flight loads with 32 MFMA),
//           vmcnt(12) -> tile t+1 regs landed (issued at top of step t-1),
//           cvt_pk -> ds_write tile t+1 into buf[(t+1)&1], lgkmcnt(0)+barrier.
// The wait on t+1 is covered by (tail of step t-1) + LOADT + full COMP body.
// LDS layout/banking = proven baseline (128B rows, chunk ^= row&7, 0 conflicts).
// Removes the separate cast_all pass entirely.
// z=0: Q = query@wq^T+bq, scaled 0.125*log2e, RoPE, pack [B,H,L,D]
// z=1: K = key@wk^T+bk, RoPE, pack [B,H,L,D]
// z=2: Vt = (wv@value^T)+bv[row], bf16 [E][CM] (pre-transposed V)
__global__ __launch_bounds__(512) void gemm_qkv(
    const float* __restrict__ query, const float* __restrict__ keyp,
    const float* __restrict__ value,
    const float* __restrict__ wq, const float* __restrict__ wk,
    const float* __restrict__ wv,
    const float* __restrict__ bq, const float* __restrict__ bk, const float* __restrict__ bv,
    u16* __restrict__ Qp, u16* __restrict__ Kp, u16* __restrict__ Vt)
{
  __shared__ u16 As[2][16384];   // [buf][256 rows][64 k] swizzled (32KB each)
  __shared__ u16 Bs[2][8192];    // [buf][128 rows][64 k] swizzled (16KB each)
  const int z = blockIdx.y;
  const int tid=threadIdx.x, lane=tid&63, wid=tid>>6;
  const int llo=lane&15, lhi=lane>>4;
  const float* Af; const float* Btf;
  if (z==0){ Af=query; Btf=wq; }
  else if (z==1){ Af=keyp; Btf=wk; }
  else { Af=wv; Btf=value; }
  int bid = blockIdx.x;                  // [0,256) per z
  int xcd = bid&7, j = bid>>3;           // j in [0,32)
  int mb, nb;
  if (z<2){ mb = xcd*4 + (j>>3); nb = j&7; }     // 32 x 8 tiles of 256x128
  else    { mb = j&3;  nb = xcd*8 + (j>>2); }    // 4 x 64 tiles (M=1024, N=8192)
  const int m0 = mb*256, n0 = nb*128;
  const int wr = wid>>1, wc = wid&1;     // 4M x 2N wave grid, 64x64 per wave
  const int rswA = llo&7;

  // per-thread staging chunk addresses (source pre-inverse-swizzled; LDS linear)
  const float* aptr[4]; int aco[4];
  #pragma unroll
  for (int i=0;i<4;i++){
    int c = tid + i*512, row=c>>3, sc=(c&7)^(row&7);
    aptr[i] = Af + (size_t)(m0+row)*CE + sc*8;
    aco[i] = c*8;
  }
  const float* bptr[2]; int bco[2];
  #pragma unroll
  for (int i=0;i<2;i++){
    int c = tid + i*512, row=c>>3, sc=(c&7)^(row&7);
    bptr[i] = Btf + (size_t)(n0+row)*CE + sc*8;
    bco[i] = c*8;
  }

  u32x4 A0[8], B0[4], A1[8], B1[4];      // double reg sets (tile parity)

#define LOADT(T, RA, RB) do{ \
  _Pragma("unroll") \
  for (int i=0;i<4;i++){ \
    asm volatile("global_load_dwordx4 %0, %2, off\n\tglobal_load_dwordx4 %1, %2, off offset:16" \
      : "=&v"(RA[2*i]), "=&v"(RA[2*i+1]) : "v"(aptr[i] + (size_t)(T)*64) : "memory"); \
  } \
  _Pragma("unroll") \
  for (int i=0;i<2;i++){ \
    asm volatile("global_load_dwordx4 %0, %2, off\n\tglobal_load_dwordx4 %1, %2, off offset:16" \
      : "=&v"(RB[2*i]), "=&v"(RB[2*i+1]) : "v"(bptr[i] + (size_t)(T)*64) : "memory"); \
  } \
}while(0)

#define CVTW(dst, lo4, hi4) do{ \
  dst.x = cvt_pk(bcf(lo4.x), bcf(lo4.y)); \
  dst.y = cvt_pk(bcf(lo4.z), bcf(lo4.w)); \
  dst.z = cvt_pk(bcf(hi4.x), bcf(hi4.y)); \
  dst.w = cvt_pk(bcf(hi4.z), bcf(hi4.w)); \
}while(0)

#define WRITET(BUF, RA, RB) do{ \
  _Pragma("unroll") \
  for (int i=0;i<4;i++){ \
    u32x4 w; CVTW(w, RA[2*i], RA[2*i+1]); \
    *(u32x4*)&As[BUF][aco[i]] = w; \
  } \
  _Pragma("unroll") \
  for (int i=0;i<2;i++){ \
    u32x4 w; CVTW(w, RB[2*i], RB[2*i+1]); \
    *(u32x4*)&Bs[BUF][bco[i]] = w; \
  } \
}while(0)

  f32x4 acc[4][4] = {};

  auto COMP = [&](int buf){
    const char* as = (const char*)As[buf];
    const char* bs = (const char*)Bs[buf];
    #pragma unroll
    for (int ks=0; ks<2; ks++){
      bf16x8 af[4], bf_[4];
      #pragma unroll
      for (int mr=0;mr<4;mr++){
        int r = wr*64+mr*16+llo;
        af[mr] = as_bf(*(const uint4*)(as + r*128 + (((ks*4+lhi)^rswA)<<4)));
      }
      #pragma unroll
      for (int nr=0;nr<4;nr++){
        int r = wc*64+nr*16+llo;
        bf_[nr] = as_bf(*(const uint4*)(bs + r*128 + (((ks*4+lhi)^rswA)<<4)));
      }
      #pragma unroll
      for (int mr=0;mr<4;mr++)
        #pragma unroll
        for (int nr=0;nr<4;nr++)
          acc[mr][nr] = __builtin_amdgcn_mfma_f32_16x16x32_bf16(af[mr], bf_[nr], acc[mr][nr], 0,0,0);
    }
  };

  // prologue: tiles 0,1 loads in flight; confirm tile0, write buf0
  LOADT(0, A0, B0);
  LOADT(1, A1, B1);
  WAITVM("12");
  WRITET(0, A0, B0);
  LGKMB;

  // steady: WRITE-LATE order. Liveness: set s is rewritten one step after its
  // tile was flushed to LDS; buf b is rewritten behind the barrier separating
  // it from its readers (all ds ops drained by LGKMB each step).
  #pragma unroll 1
  for (int jj=0; jj<7; jj++){
    const int t = 2*jj;
    // even step t: issue t+2 -> set0; compute tile t (buf0); confirm t+1; write buf1
    LOADT(t+2, A0, B0);
    COMP(0);
    WAITVM("12");
    WRITET(1, A1, B1);
    LGKMB;
    // odd step t+1: issue t+3 -> set1; compute tile t+1 (buf1); confirm t+2; write buf0
    LOADT(t+3, A1, B1);
    COMP(1);
    WAITVM("12");
    WRITET(0, A0, B0);
    LGKMB;
  }
  // t=14: compute buf0; confirm tile15 (set1); write buf1
  COMP(0);
  WAITVM("0");
  WRITET(1, A1, B1);
  LGKMB;
  COMP(1);                               // t=15; epilogue touches no LDS

#undef LOADT
#undef WRITET

  const int colbase = n0 + wc*64;
  if (z < 2){
    const float* bias = z ? bk : bq;
    u16* outp = z ? Kp : Qp;
    const float scale = z ? 1.f : 0.125f*LOG2E;
    const int h = colbase >> 6;           // wave covers exactly one head
    float b1[2], b2[2], invr[2];
    #pragma unroll
    for (int nr=0;nr<2;nr++){
      int j2 = nr*16 + llo;
      b1[nr] = bias[colbase + j2];
      b2[nr] = bias[colbase + j2 + 32];
      invr[nr] = exp2f(-(float)j2 * 0.41524101186092033f) * INV2PI;  // 10000^{-j2/32}/(2pi)
    }
    #pragma unroll
    for (int mr=0;mr<4;mr++)
      #pragma unroll
      for (int r=0;r<4;r++){
        int row = m0 + wr*64 + mr*16 + lhi*4 + r;
        int b = row >> 11, l = row & 2047;
        u16* dst = outp + (((size_t)(b*CH + h)*CL + l) << 6);
        #pragma unroll
        for (int nr=0;nr<2;nr++){
          int j2 = nr*16 + llo;
          float x1 = (acc[mr][nr][r]   + b1[nr]) * scale;
          float x2 = (acc[mr][nr+2][r] + b2[nr]) * scale;
          float fr = fractf_((float)l * invr[nr]);
          float sn = sinrev(fr), cs = cosrev(fr);
          dst[j2]      = f2bf(x1*cs - x2*sn);
          dst[j2 + 32] = f2bf(x2*cs + x1*sn);
        }
      }
  } else {
    #pragma unroll
    for (int mr=0;mr<4;mr++)
      #pragma unroll
      for (int r=0;r<4;r++){
        int row = m0 + wr*64 + mr*16 + lhi*4 + r;
        float bvv = bv[row];
        #pragma unroll
        for (int nr=0;nr<4;nr++){
          int col = colbase + nr*16 + llo;
          Vt[(size_t)row*CM + col] = f2bf(acc[mr][nr][r] + bvv);
        }
      }
  }
}

// ---------------- output projection GEMM (fp32 out, bias per col) ----------------
// A = AO bf16 via global_load_lds ring-3; B = wo fp32 reg-staged (cast in staging).
// WRITE-LATE step order, mixed ledger: 8 outstanding per tile (A:4 lds + B:4 reg).
__global__ __launch_bounds__(512) void gemm_out(
    const u16* __restrict__ A, const float* __restrict__ Btf,
    const float* __restrict__ bias, float* __restrict__ C)
{
  __shared__ u16 As[3][16384];   // 48KB
  __shared__ u16 Bs[2][8192];    // 32KB
  const int tid=threadIdx.x, lane=tid&63, wid=tid>>6;
  const int llo=lane&15, lhi=lane>>4;
  int bid = blockIdx.x;
  int xcd = bid&7, j = bid>>3;
  const int m0 = (xcd*4 + (j>>3))*256, n0 = (j&7)*128;   // 32 x 8 tiles of 256x128
  const int wr = wid>>1, wc = wid&1;
  const int rswA = llo&7;

  auto STAGEA = [&](int t, int buf){     // 4 gload_lds / thread
    #pragma unroll
    for (int i=0;i<4;i++){
      int c = tid + i*512, row=c>>3, sc=(c&7)^(row&7);
      __builtin_amdgcn_global_load_lds(GP(A + (size_t)(m0+row)*CE + t*64 + sc*8),
                                       LP(&As[buf][c*8]), 16, 0, 0);
    }
  };

  const float* bptr[2]; int bco[2];
  #pragma unroll
  for (int i=0;i<2;i++){
    int c = tid + i*512, row=c>>3, sc=(c&7)^(row&7);
    bptr[i] = Btf + (size_t)(n0+row)*CE + sc*8;
    bco[i] = c*8;
  }
  u32x4 B0[4], B1[4];

#define LOADB(T, RB) do{ \
  _Pragma("unroll") \
  for (int i=0;i<2;i++){ \
    asm volatile("global_load_dwordx4 %0, %2, off\n\tglobal_load_dwordx4 %1, %2, off offset:16" \
      : "=&v"(RB[2*i]), "=&v"(RB[2*i+1]) : "v"(bptr[i] + (size_t)(T)*64) : "memory"); \
  } \
}while(0)

#define WRITEB(BUF, RB) do{ \
  _Pragma("unroll") \
  for (int i=0;i<2;i++){ \
    u32x4 w; CVTW(w, RB[2*i], RB[2*i+1]); \
    *(u32x4*)&Bs[BUF][bco[i]] = w; \
  } \
}while(0)

  f32x4 acc[4][4] = {};

  auto COMP = [&](int abuf, int bbuf){
    const char* as = (const char*)As[abuf];
    const char* bs = (const char*)Bs[bbuf];
    #pragma unroll
    for (int ks=0; ks<2; ks++){
      bf16x8 af[4], bf_[4];
      #pragma unroll
      for (int mr=0;mr<4;mr++){
        int r = wr*64+mr*16+llo;
        af[mr] = as_bf(*(const uint4*)(as + r*128 + (((ks*4+lhi)^rswA)<<4)));
      }
      #pragma unroll
      for (int nr=0;nr<4;nr++){
        int r = wc*64+nr*16+llo;
        bf_[nr] = as_bf(*(const uint4*)(bs + r*128 + (((ks*4+lhi)^rswA)<<4)));
      }
      #pragma unroll
      for (int mr=0;mr<4;mr++)
        #pragma unroll
        for (int nr=0;nr<4;nr++)
          acc[mr][nr] = __builtin_amdgcn_mfma_f32_16x16x32_bf16(af[mr], bf_[nr], acc[mr][nr], 0,0,0);
    }
  };

  // prologue: A(0),B(0),A(1),B(1) in flight; confirm tile0 pair, write B0
  STAGEA(0,0); LOADB(0, B0);
  STAGEA(1,1); LOADB(1, B1);
  WAITVM("8");
  WRITEB(0, B0);
  LGKMB;

  #pragma unroll 1
  for (int jj=0; jj<7; jj++){
    const int t = 2*jj;
    STAGEA(t+2, (t+2)%3); LOADB(t+2, B0);
    COMP(t%3, 0);
    WAITVM("8");
    WRITEB(1, B1);
    LGKMB;
    STAGEA(t+3, (t+3)%3); LOADB(t+3, B1);
    COMP((t+1)%3, 1);
    WAITVM("8");
    WRITEB(0, B0);
    LGKMB;
  }
  COMP(2, 0);          // t=14
  WAITVM("0");
  WRITEB(1, B1);
  LGKMB;
  COMP(0, 1);          // t=15

#undef LOADB
#undef WRITEB

  #pragma unroll
  for (int mr=0;mr<4;mr++)
    #pragma unroll
    for (int nr=0;nr<4;nr++)
      #pragma unroll
      for (int r=0;r<4;r++){
        int row = m0 + wr*64 + mr*16 + lhi*4 + r;
        int col = n0 + wc*64 + nr*16 + llo;
        C[(size_t)row*CE + col] = acc[mr][nr][r] + bias[col];
      }
}

// ---------------- flash attention, swapped-operand 32x32, counted-vmcnt ring ----------------
// Qp,Kp: [B*H, L, D] bf16 (Q pre-scaled by 0.125*log2e). Vt: [E, CM] bf16. Out AO [B,L,E] bf16.
__global__ __launch_bounds__(256,2) void attn_kernel(
    const u16* __restrict__ Qp, const u16* __restrict__ Kp, const u16* __restrict__ Vt,
    const float* __restrict__ maskf, u16* __restrict__ AO)
{
  __shared__ u16 K_lds[4][4096];   // ring of [kv64][d64] swizzled tiles
  __shared__ u16 V_lds[4][4096];   // ring of [d64][kv64] swizzled tiles
  __shared__ float M_lds[2048];    // padding mask row (exp2 domain) for this batch
  const int bh = blockIdx.x;
  const int slot = blockIdx.y;
  const int b = bh >> 4, h = bh & 15;
  const int tid=threadIdx.x, lane=tid&63, wid=tid>>6;
  const int l31 = lane&31, hi = lane>>5;
  const u16* Qh = Qp + (size_t)bh*CL*CD;
  const u16* Kh = Kp + (size_t)bh*CL*CD;
  const u16* Vhd = Vt + (size_t)(h*CD)*CM + b*CL;

  // stage padding-mask row once (8KB). Issued FIRST so the t=0 vmcnt(8) covers it.
  #pragma unroll
  for (int i=0;i<2;i++)
    __builtin_amdgcn_global_load_lds(GP(maskf + b*CL + (i*256+tid)*4),
                                     LP(&M_lds[(i*256+tid)*4]), 16, 0, 0);

  auto STAGE = [&](int t, int buf){   // 4 gload_lds instructions per wave
    const u16* Ksrc = Kh + t*64*CD;
    const u16* Vsrc = Vhd + t*64;
    #pragma unroll
    for (int i=0;i<2;i++){
      int c = tid + i*256;
      int row = c>>3, sc = c&7;
      int c16 = sc ^ (row&7);
      __builtin_amdgcn_global_load_lds(GP(Ksrc + row*CD + c16*8),
                                       LP(&K_lds[buf][c*8]), 16, 0, 0);
      __builtin_amdgcn_global_load_lds(GP(Vsrc + (size_t)row*CM + c16*8),
                                       LP(&V_lds[buf][c*8]), 16, 0, 0);
    }
  };

  const int rowb = l31*128;            // LDS row byte base
  const int rsw  = (l31&7)<<4;
  const int qts2[2] = {15-slot, slot};

  for (int qi=0; qi<2; qi++){
    const int qt = qts2[qi];
    const int qw0 = qt*128 + wid*32;
    const int qlane = qw0 + l31;

    bf16x8 qf[4];
    #pragma unroll
    for (int c=0;c<4;c++)
      qf[c] = as_bf(*(const uint4*)(Qh + (size_t)qlane*CD + c*16 + hi*8));

    f32x16 o0 = {}, o1 = {};
    float m_r = -3e38f, l_r = 0.f;

    const int nt = qt*2 + 2;
    STAGE(0,0); STAGE(1,1);

    for (int t=0; t<nt; t++){
      // vmcnt ledger: entering iter t, {S(t),S(t+1)} = 8 outstanding (each 4/wave)
      if (t+2 < nt){ STAGE(t+2,(t+2)&3); WAITB("8"); }
      else if (t+1 < nt){ WAITB("4"); }
      else { WAITB("0"); }

      const int kv0 = t*64;
      const char* kb = (const char*)K_lds[t&3];
      const char* vb = (const char*)V_lds[t&3];

      // ---- padding mask (broadcast LDS reads; issue early to overlap MFMA)
      f32x4 cm[8];
      #pragma unroll
      for (int s2=0;s2<2;s2++)
        #pragma unroll
        for (int g=0; g<4; g++)
          cm[s2*4+g] = *(const f32x4*)&M_lds[kv0 + s2*32 + g*8 + hi*4];

      // ---- S^T = K @ Q^T  (two 32x32 tiles over kv); Q carries 0.125*log2e
      f32x16 s0 = {}, s1 = {};
      __builtin_amdgcn_s_setprio(1);
      #pragma unroll
      for (int c=0;c<4;c++){
        int cb = (c*32 + hi*16) ^ rsw;
        bf16x8 k0 = as_bf(*(const uint4*)(kb + rowb + cb));
        bf16x8 k1 = as_bf(*(const uint4*)(kb + 4096 + rowb + cb));
        s0 = __builtin_amdgcn_mfma_f32_32x32x16_bf16(k0, qf[c], s0, 0,0,0);
        s1 = __builtin_amdgcn_mfma_f32_32x32x16_bf16(k1, qf[c], s1, 0,0,0);
      }
      __builtin_amdgcn_s_setprio(0);

      // ---- v = s + mask (+ causal on diagonal tiles), in place (exp2 domain)
      if (kv0 + 63 > qw0){
        #pragma unroll
        for (int s2=0;s2<2;s2++){
          f32x16& sv = s2 ? s1 : s0;
          #pragma unroll
          for (int reg=0; reg<16; reg++){
            int k = kv0 + s2*32 + (reg&3) + (reg>>2)*8 + hi*4;
            float v = sv[reg] + cm[s2*4+(reg>>2)][reg&3];
            sv[reg] = (k > qlane) ? v + NEGBIG : v;
          }
        }
      } else {
        #pragma unroll
        for (int s2=0;s2<2;s2++){
          f32x16& sv = s2 ? s1 : s0;
          #pragma unroll
          for (int reg=0; reg<16; reg++)
            sv[reg] = sv[reg] + cm[s2*4+(reg>>2)][reg&3];
        }
      }

      // ---- row max (pairwise + v_max3 tree + partner swap)
      f32x16 mx;
      #pragma unroll
      for (int r=0;r<16;r++) mx[r] = fmaxf(s0[r], s1[r]);
      float a0 = max3f(mx[0],mx[1],mx[2]);
      float a1 = max3f(mx[3],mx[4],mx[5]);
      float a2 = max3f(mx[6],mx[7],mx[8]);
      float a3 = max3f(mx[9],mx[10],mx[11]);
      float a4 = max3f(mx[12],mx[13],mx[14]);
      float vmax = fmaxf(max3f(a0,a1,a2), max3f(a3,a4,mx[15]));
      vmax = fmaxf(vmax, __shfl_xor(vmax, 32));

      // ---- defer-max (T13): rescale only when max grew by > THR (log2 units)
      if (__any(vmax > m_r + 12.0f)){
        float mnew = fmaxf(m_r, vmax);
        float sc = fexp2(m_r - mnew);
        l_r *= sc;
        o0 *= sc; o1 *= sc;
        m_r = mnew;
      }

      // ---- p = exp2(v - m), in place (p <= 2^12)
      #pragma unroll
      for (int r=0;r<16;r++){
        s0[r] = fexp2(s0[r] - m_r);
        s1[r] = fexp2(s1[r] - m_r);
      }
      // ---- row sum
      f32x16 sm = s0 + s1;
      #pragma unroll
      for (int w=8; w>=1; w>>=1)
        #pragma unroll
        for (int r=0;r<w;r++) sm[r] = sm[r] + sm[r+w];
      float rsum = sm[0];
      rsum += __shfl_xor(rsum, 32);
      l_r += rsum;

      // ---- P -> bf16 B-fragments in-register (cvt_pk + permlane32_swap)
      u32 w_[16];
      #pragma unroll
      for (int s2=0;s2<2;s2++){
        f32x16& sv = s2 ? s1 : s0;
        #pragma unroll
        for (int c=0;c<2;c++){
          u32 a  = cvt_pk(sv[c*8+0], sv[c*8+1]);
          u32 bb = cvt_pk(sv[c*8+2], sv[c*8+3]);
          u32 cc = cvt_pk(sv[c*8+4], sv[c*8+5]);
          u32 dd = cvt_pk(sv[c*8+6], sv[c*8+7]);
          plswap(a, cc); plswap(bb, dd);
          int base = (s2*2+c)*4;
          w_[base+0]=a; w_[base+1]=bb; w_[base+2]=cc; w_[base+3]=dd;
        }
      }

      // ---- O^T += V^T @ P^T
      __builtin_amdgcn_s_setprio(1);
      #pragma unroll
      for (int kc=0; kc<4; kc++){
        bf16x8 pf = as_bf(make_uint4(w_[kc*4], w_[kc*4+1], w_[kc*4+2], w_[kc*4+3]));
        int cb = (kc*32 + hi*16) ^ rsw;
        bf16x8 v0 = as_bf(*(const uint4*)(vb + rowb + cb));
        bf16x8 v1 = as_bf(*(const uint4*)(vb + 4096 + rowb + cb));
        o0 = __builtin_amdgcn_mfma_f32_32x32x16_bf16(v0, pf, o0, 0,0,0);
        o1 = __builtin_amdgcn_mfma_f32_32x32x16_bf16(v1, pf, o1, 0,0,0);
      }
      __builtin_amdgcn_s_setprio(0);
      // no trailing barrier: ring depth 4 + per-iter barrier bounds wave skew safely
    }

    // ---- normalize + write O^T: lane has q=qlane, d = mt*32 + g*8 + hi*4 + {0..3}
    float inv = 1.f / l_r;
    u16* dst = AO + (size_t)(b*CL + qlane)*CE + h*CD;
    #pragma unroll
    for (int mt=0; mt<2; mt++){
      f32x16& ov = mt ? o1 : o0;
      #pragma unroll
      for (int g=0; g<4; g++){
        u32 lo  = cvt_pk(ov[g*4+0]*inv, ov[g*4+1]*inv);
        u32 hi2 = cvt_pk(ov[g*4+2]*inv, ov[g*4+3]*inv);
        *(uint2*)(dst + mt*32 + g*8 + hi*4) = make_uint2(lo, hi2);
      }
    }
    // drain + protect ring reuse by qi=1 prologue (and reset vmcnt ledger)
    __syncthreads();
  }
}

// ---------------- launcher ----------------
extern "C" void kernel_launch(void* const* d_in, const int* in_sizes, int n_in,
                              void* d_out, int out_size, void* d_ws, size_t ws_size,
                              hipStream_t stream) {
  const float* query = (const float*)d_in[0];
  const float* key_  = (const float*)d_in[1];
  const float* value = (const float*)d_in[2];
  const float* wq = (const float*)d_in[3];
  const float* bq = (const float*)d_in[4];
  const float* wk = (const float*)d_in[5];
  const float* bk = (const float*)d_in[6];
  const float* wv = (const float*)d_in[7];
  const float* bv = (const float*)d_in[8];
  const float* wo = (const float*)d_in[9];
  const float* bo = (const float*)d_in[10];
  const void*  kpm = d_in[11];

  char* ws = (char*)d_ws;
  constexpr size_t SZ_ME_BF = (size_t)CM*CE*2;    // 16 MiB
  constexpr size_t OFF_FLAG = 0;
  constexpr size_t OFF_MASKF= 256;
  constexpr size_t OFF_AO   = 65536;              // attn output, bf16 [B,L,E]
  constexpr size_t OFF_KP   = OFF_AO + SZ_ME_BF;
  constexpr size_t OFF_VT   = OFF_KP + SZ_ME_BF;  // Vt [1024][8192]
  constexpr size_t OFF_QP   = OFF_VT + SZ_ME_BF;

  int*   flag  = (int*)(ws + OFF_FLAG);
  float* maskf = (float*)(ws + OFF_MASKF);
  u16*  AO  = (u16*)(ws + OFF_AO);
  u16*  Kp  = (u16*)(ws + OFF_KP);
  u16*  Vt  = (u16*)(ws + OFF_VT);
  u16*  Qp  = (u16*)(ws + OFF_QP);

  detect_mask_kernel<<<1,256,0,stream>>>(kpm, flag);
  convert_mask_kernel<<<(CB*CL+255)/256,256,0,stream>>>(kpm, flag, maskf);

  // projections read fp32 inputs directly (cast fused into staging) — no cast pass
  gemm_qkv<<<dim3(256,3),512,0,stream>>>(query, key_, value, wq, wk, wv,
                                         bq, bk, bv, Qp, Kp, Vt);

  attn_kernel<<<dim3(CB*CH, 8),256,0,stream>>>(Qp, Kp, Vt, maskf, AO);

  gemm_out<<<256,512,0,stream>>>(AO, wo, bo, (float*)d_out);
}

// Round 6
// 190.444 us; speedup vs baseline: 1.0117x; 1.0117x over previous
//
#include <hip/hip_runtime.h>

typedef unsigned short u16;
typedef unsigned int   u32;

using bf16x8 = __attribute__((ext_vector_type(8))) __bf16;
using f32x4  = __attribute__((ext_vector_type(4))) float;
using f32x16 = __attribute__((ext_vector_type(16))) float;
using u32x4  = __attribute__((ext_vector_type(4))) u32;

#define DEV static __device__ __forceinline__
#define GP(p) (const __attribute__((address_space(1))) void*)(p)
#define LP(p) (__attribute__((address_space(3))) void*)(p)
// fused counted-wait + barrier (T4)
#define WAITB(N) asm volatile("s_waitcnt vmcnt(" N ")\n\ts_barrier" ::: "memory")
// counted VMEM wait for reg-staged loads; sched_barrier pins register-only consumers (rule #18)
#define WAITVM(N) do{ asm volatile("s_waitcnt vmcnt(" N ")" ::: "memory"); \
                      __builtin_amdgcn_sched_barrier(0); }while(0)
// end-of-step: drain LDS ops then barrier
#define LGKMB asm volatile("s_waitcnt lgkmcnt(0)\n\ts_barrier" ::: "memory")

DEV u16 f2bf(float f){                      // RNE float->bf16
  u32 u = __builtin_bit_cast(u32, f);
  u32 r = u + 0x7fffu + ((u>>16)&1u);
  return (u16)(r>>16);
}
DEV float bcf(u32 x){ return __builtin_bit_cast(float, x); }
DEV bf16x8 as_bf(uint4 v){ return __builtin_bit_cast(bf16x8, v); }
DEV u32 cvt_pk(float lo, float hi){
  u32 r;
  asm("v_cvt_pk_bf16_f32 %0, %1, %2" : "=v"(r) : "v"(lo), "v"(hi));
  return r;
}
DEV void plswap(u32 &a, u32 &b){
  auto r = __builtin_amdgcn_permlane32_swap((int)a, (int)b, false, false);
  a = (u32)r[0]; b = (u32)r[1];
}
DEV float fexp2(float x){ float r; asm("v_exp_f32 %0, %1" : "=v"(r) : "v"(x)); return r; }
DEV float max3f(float a, float b, float c){
  float r; asm("v_max3_f32 %0, %1, %2, %3" : "=v"(r) : "v"(a), "v"(b), "v"(c)); return r;
}
DEV float fractf_(float x){ float r; asm("v_fract_f32 %0, %1" : "=v"(r) : "v"(x)); return r; }
DEV float sinrev(float f){ float r; asm("v_sin_f32 %0, %1" : "=v"(r) : "v"(f)); return r; }
DEV float cosrev(float f){ float r; asm("v_cos_f32 %0, %1" : "=v"(r) : "v"(f)); return r; }

// problem constants
constexpr int CB = 4, CL = 2048, CE = 1024, CH = 16, CD = 64;
constexpr int CM = CB*CL;           // 8192 rows
constexpr float LOG2E  = 1.44269504088896f;
constexpr float NEGBIG = -1.44269504e9f;    // -1e9 * log2e (exp2 domain)
constexpr float INV2PI = 0.15915494309189535f;

// ---------------- mask detect + convert, single launch ----------------
// Each of 32 blocks redundantly scans the 8KB mask head (L2-hot) for dtype
// detection, then converts its own 256-element slice. Saves a launch.
__global__ void mask_kernel(const void* __restrict__ mask, float* __restrict__ maskf){
  __shared__ int a_gt1, a_badf, a_oddnz, a_evennz;
  if (threadIdx.x==0){ a_gt1=0; a_badf=0; a_oddnz=0; a_evennz=0; }
  __syncthreads();
  const u32* w = (const u32*)mask;
  int gt1=0, badf=0, oddnz=0, evennz=0;
  for (int i=threadIdx.x; i<2048; i+=256){
    u32 v = w[i];
    if (v > 1u) gt1 = 1;
    if (v != 0u && v != 0x3f800000u) badf = 1;
    if (v != 0u){ if (i & 1) oddnz = 1; else evennz = 1; }
  }
  if (gt1) atomicOr(&a_gt1,1);
  if (badf) atomicOr(&a_badf,1);
  if (oddnz) atomicOr(&a_oddnz,1);
  if (evennz) atomicOr(&a_evennz,1);
  __syncthreads();
  int mode;
  if (!a_gt1)           mode = (!a_oddnz && a_evennz) ? 3 : 0;
  else if (!a_badf)     mode = 1;
  else                  mode = 2;
  int i = blockIdx.x*blockDim.x + threadIdx.x;   // B*L (grid covers exactly 8192)
  int v;
  if      (mode==0) v = ((const int*)mask)[i] != 0;
  else if (mode==1) v = ((const float*)mask)[i] != 0.f;
  else if (mode==3) v = ((const int*)mask)[2*i] != 0;
  else              v = ((const unsigned char*)mask)[i] != 0;
  maskf[i] = v ? NEGBIG : 0.f;
}

// ---------------- QKV projection GEMM, fp32 sources, fused cast-in-staging ----------------
// 256x128 tile, 8 waves, BK=64, ring-2 LDS + double reg sets (R4 step order, best measured):
//   step t: issue global_load_dwordx4 for tile t+2 (12 loads, set t&1),
//           vmcnt(12) -> tile t+1 regs landed (issued one full step earlier),
//           cvt_pk -> ds_write tile t+1 into buf[(t+1)&1],
//           COMP(t) from buf[t&1], lgkmcnt(0)+barrier.
// LDS layout/banking = proven baseline (128B rows, chunk ^= row&7, 0 conflicts).
// z=0: Q = query@wq^T+bq, scaled 0.125*log2e, RoPE, pack [B,H,L,D]
// z=1: K = key@wk^T+bk, RoPE, pack [B,H,L,D]
// z=2: Vt = (wv@value^T)+bv[row], bf16 [E][CM] (pre-transposed V)
__global__ __launch_bounds__(512) void gemm_qkv(
    const float* __restrict__ query, const float* __restrict__ keyp,
    const float* __restrict__ value,
    const float* __restrict__ wq, const float* __restrict__ wk,
    const float* __restrict__ wv,
    const float* __restrict__ bq, const float* __restrict__ bk, const float* __restrict__ bv,
    u16* __restrict__ Qp, u16* __restrict__ Kp, u16* __restrict__ Vt)
{
  __shared__ u16 As[2][16384];   // [buf][256 rows][64 k] swizzled (32KB each)
  __shared__ u16 Bs[2][8192];    // [buf][128 rows][64 k] swizzled (16KB each)
  const int z = blockIdx.y;
  const int tid=threadIdx.x, lane=tid&63, wid=tid>>6;
  const int llo=lane&15, lhi=lane>>4;
  const float* Af; const float* Btf;
  if (z==0){ Af=query; Btf=wq; }
  else if (z==1){ Af=keyp; Btf=wk; }
  else { Af=wv; Btf=value; }
  int bid = blockIdx.x;                  // [0,256) per z
  int xcd = bid&7, j = bid>>3;           // j in [0,32)
  int mb, nb;
  if (z<2){ mb = xcd*4 + (j>>3); nb = j&7; }     // 32 x 8 tiles of 256x128
  else    { mb = j&3;  nb = xcd*8 + (j>>2); }    // 4 x 64 tiles (M=1024, N=8192)
  const int m0 = mb*256, n0 = nb*128;
  const int wr = wid>>1, wc = wid&1;     // 4M x 2N wave grid, 64x64 per wave
  const int rswA = llo&7;

  // per-thread staging chunk addresses (source pre-inverse-swizzled; LDS linear)
  const float* aptr[4]; int aco[4];
  #pragma unroll
  for (int i=0;i<4;i++){
    int c = tid + i*512, row=c>>3, sc=(c&7)^(row&7);
    aptr[i] = Af + (size_t)(m0+row)*CE + sc*8;
    aco[i] = c*8;
  }
  const float* bptr[2]; int bco[2];
  #pragma unroll
  for (int i=0;i<2;i++){
    int c = tid + i*512, row=c>>3, sc=(c&7)^(row&7);
    bptr[i] = Btf + (size_t)(n0+row)*CE + sc*8;
    bco[i] = c*8;
  }

  u32x4 A0[8], B0[4], A1[8], B1[4];      // double reg sets (tile parity)

#define LOADT(T, RA, RB) do{ \
  _Pragma("unroll") \
  for (int i=0;i<4;i++){ \
    asm volatile("global_load_dwordx4 %0, %2, off\n\tglobal_load_dwordx4 %1, %2, off offset:16" \
      : "=&v"(RA[2*i]), "=&v"(RA[2*i+1]) : "v"(aptr[i] + (size_t)(T)*64) : "memory"); \
  } \
  _Pragma("unroll") \
  for (int i=0;i<2;i++){ \
    asm volatile("global_load_dwordx4 %0, %2, off\n\tglobal_load_dwordx4 %1, %2, off offset:16" \
      : "=&v"(RB[2*i]), "=&v"(RB[2*i+1]) : "v"(bptr[i] + (size_t)(T)*64) : "memory"); \
  } \
}while(0)

#define CVTW(dst, lo4, hi4) do{ \
  dst.x = cvt_pk(bcf(lo4.x), bcf(lo4.y)); \
  dst.y = cvt_pk(bcf(lo4.z), bcf(lo4.w)); \
  dst.z = cvt_pk(bcf(hi4.x), bcf(hi4.y)); \
  dst.w = cvt_pk(bcf(hi4.z), bcf(hi4.w)); \
}while(0)

#define WRITET(BUF, RA, RB) do{ \
  _Pragma("unroll") \
  for (int i=0;i<4;i++){ \
    u32x4 w; CVTW(w, RA[2*i], RA[2*i+1]); \
    *(u32x4*)&As[BUF][aco[i]] = w; \
  } \
  _Pragma("unroll") \
  for (int i=0;i<2;i++){ \
    u32x4 w; CVTW(w, RB[2*i], RB[2*i+1]); \
    *(u32x4*)&Bs[BUF][bco[i]] = w; \
  } \
}while(0)

  f32x4 acc[4][4] = {};

  auto COMP = [&](int buf){
    const char* as = (const char*)As[buf];
    const char* bs = (const char*)Bs[buf];
    #pragma unroll
    for (int ks=0; ks<2; ks++){
      bf16x8 af[4], bf_[4];
      #pragma unroll
      for (int mr=0;mr<4;mr++){
        int r = wr*64+mr*16+llo;
        af[mr] = as_bf(*(const uint4*)(as + r*128 + (((ks*4+lhi)^rswA)<<4)));
      }
      #pragma unroll
      for (int nr=0;nr<4;nr++){
        int r = wc*64+nr*16+llo;
        bf_[nr] = as_bf(*(const uint4*)(bs + r*128 + (((ks*4+lhi)^rswA)<<4)));
      }
      #pragma unroll
      for (int mr=0;mr<4;mr++)
        #pragma unroll
        for (int nr=0;nr<4;nr++)
          acc[mr][nr] = __builtin_amdgcn_mfma_f32_16x16x32_bf16(af[mr], bf_[nr], acc[mr][nr], 0,0,0);
    }
  };

  // prologue: tiles 0,1 loads in flight; confirm tile0, write buf0
  LOADT(0, A0, B0);
  LOADT(1, A1, B1);
  WAITVM("12");
  WRITET(0, A0, B0);
  LGKMB;

  // steady: 16 K-tiles, unrolled x2 for static reg-set selection (R4 order)
  #pragma unroll 1
  for (int jj=0; jj<7; jj++){
    const int t = 2*jj;
    LOADT(t+2, A0, B0);
    WAITVM("12");
    WRITET(1, A1, B1);
    COMP(0);
    LGKMB;
    LOADT(t+3, A1, B1);
    WAITVM("12");
    WRITET(0, A0, B0);
    COMP(1);
    LGKMB;
  }
  // t=14: tile15 (set1) is the last in flight
  WAITVM("0");
  WRITET(1, A1, B1);
  COMP(0);
  LGKMB;
  COMP(1);                               // t=15; epilogue touches no LDS

#undef LOADT
#undef WRITET

  const int colbase = n0 + wc*64;
  if (z < 2){
    const float* bias = z ? bk : bq;
    u16* outp = z ? Kp : Qp;
    const float scale = z ? 1.f : 0.125f*LOG2E;
    const int h = colbase >> 6;           // wave covers exactly one head
    float b1[2], b2[2], invr[2];
    #pragma unroll
    for (int nr=0;nr<2;nr++){
      int j2 = nr*16 + llo;
      b1[nr] = bias[colbase + j2];
      b2[nr] = bias[colbase + j2 + 32];
      invr[nr] = exp2f(-(float)j2 * 0.41524101186092033f) * INV2PI;  // 10000^{-j2/32}/(2pi)
    }
    #pragma unroll
    for (int mr=0;mr<4;mr++)
      #pragma unroll
      for (int r=0;r<4;r++){
        int row = m0 + wr*64 + mr*16 + lhi*4 + r;
        int b = row >> 11, l = row & 2047;
        u16* dst = outp + (((size_t)(b*CH + h)*CL + l) << 6);
        #pragma unroll
        for (int nr=0;nr<2;nr++){
          int j2 = nr*16 + llo;
          float x1 = (acc[mr][nr][r]   + b1[nr]) * scale;
          float x2 = (acc[mr][nr+2][r] + b2[nr]) * scale;
          float fr = fractf_((float)l * invr[nr]);
          float sn = sinrev(fr), cs = cosrev(fr);
          dst[j2]      = f2bf(x1*cs - x2*sn);
          dst[j2 + 32] = f2bf(x2*cs + x1*sn);
        }
      }
  } else {
    #pragma unroll
    for (int mr=0;mr<4;mr++)
      #pragma unroll
      for (int r=0;r<4;r++){
        int row = m0 + wr*64 + mr*16 + lhi*4 + r;
        float bvv = bv[row];
        #pragma unroll
        for (int nr=0;nr<4;nr++){
          int col = colbase + nr*16 + llo;
          Vt[(size_t)row*CM + col] = f2bf(acc[mr][nr][r] + bvv);
        }
      }
  }
}

// ---------------- output projection GEMM (fp32 out, bias per col) ----------------
// A = AO bf16 via global_load_lds ring-3; B = wo fp32 reg-staged (cast in staging).
__global__ __launch_bounds__(512) void gemm_out(
    const u16* __restrict__ A, const float* __restrict__ Btf,
    const float* __restrict__ bias, float* __restrict__ C)
{
  __shared__ u16 As[3][16384];   // 48KB
  __shared__ u16 Bs[2][8192];    // 32KB
  const int tid=threadIdx.x, lane=tid&63, wid=tid>>6;
  const int llo=lane&15, lhi=lane>>4;
  int bid = blockIdx.x;
  int xcd = bid&7, j = bid>>3;
  const int m0 = (xcd*4 + (j>>3))*256, n0 = (j&7)*128;   // 32 x 8 tiles of 256x128
  const int wr = wid>>1, wc = wid&1;
  const int rswA = llo&7;

  auto STAGEA = [&](int t, int buf){     // 4 gload_lds / thread
    #pragma unroll
    for (int i=0;i<4;i++){
      int c = tid + i*512, row=c>>3, sc=(c&7)^(row&7);
      __builtin_amdgcn_global_load_lds(GP(A + (size_t)(m0+row)*CE + t*64 + sc*8),
                                       LP(&As[buf][c*8]), 16, 0, 0);
    }
  };

  const float* bptr[2]; int bco[2];
  #pragma unroll
  for (int i=0;i<2;i++){
    int c = tid + i*512, row=c>>3, sc=(c&7)^(row&7);
    bptr[i] = Btf + (size_t)(n0+row)*CE + sc*8;
    bco[i] = c*8;
  }
  u32x4 B0[4], B1[4];

#define LOADB(T, RB) do{ \
  _Pragma("unroll") \
  for (int i=0;i<2;i++){ \
    asm volatile("global_load_dwordx4 %0, %2, off\n\tglobal_load_dwordx4 %1, %2, off offset:16" \
      : "=&v"(RB[2*i]), "=&v"(RB[2*i+1]) : "v"(bptr[i] + (size_t)(T)*64) : "memory"); \
  } \
}while(0)

#define WRITEB(BUF, RB) do{ \
  _Pragma("unroll") \
  for (int i=0;i<2;i++){ \
    u32x4 w; CVTW(w, RB[2*i], RB[2*i+1]); \
    *(u32x4*)&Bs[BUF][bco[i]] = w; \
  } \
}while(0)

  f32x4 acc[4][4] = {};

  auto COMP = [&](int abuf, int bbuf){
    const char* as = (const char*)As[abuf];
    const char* bs = (const char*)Bs[bbuf];
    #pragma unroll
    for (int ks=0; ks<2; ks++){
      bf16x8 af[4], bf_[4];
      #pragma unroll
      for (int mr=0;mr<4;mr++){
        int r = wr*64+mr*16+llo;
        af[mr] = as_bf(*(const uint4*)(as + r*128 + (((ks*4+lhi)^rswA)<<4)));
      }
      #pragma unroll
      for (int nr=0;nr<4;nr++){
        int r = wc*64+nr*16+llo;
        bf_[nr] = as_bf(*(const uint4*)(bs + r*128 + (((ks*4+lhi)^rswA)<<4)));
      }
      #pragma unroll
      for (int mr=0;mr<4;mr++)
        #pragma unroll
        for (int nr=0;nr<4;nr++)
          acc[mr][nr] = __builtin_amdgcn_mfma_f32_16x16x32_bf16(af[mr], bf_[nr], acc[mr][nr], 0,0,0);
    }
  };

  // prologue: A(0),B(0),A(1),B(1) in flight; confirm tile0 pair, write B0
  STAGEA(0,0); LOADB(0, B0);
  STAGEA(1,1); LOADB(1, B1);
  WAITVM("8");
  WRITEB(0, B0);
  LGKMB;

  #pragma unroll 1
  for (int jj=0; jj<7; jj++){
    const int t = 2*jj;
    STAGEA(t+2, (t+2)%3); LOADB(t+2, B0);
    WAITVM("8");
    WRITEB(1, B1);
    COMP(t%3, 0);
    LGKMB;
    STAGEA(t+3, (t+3)%3); LOADB(t+3, B1);
    WAITVM("8");
    WRITEB(0, B0);
    COMP((t+1)%3, 1);
    LGKMB;
  }
  WAITVM("0");
  WRITEB(1, B1);
  COMP(2, 0);          // t=14
  LGKMB;
  COMP(0, 1);          // t=15

#undef LOADB
#undef WRITEB

  #pragma unroll
  for (int mr=0;mr<4;mr++)
    #pragma unroll
    for (int nr=0;nr<4;nr++)
      #pragma unroll
      for (int r=0;r<4;r++){
        int row = m0 + wr*64 + mr*16 + lhi*4 + r;
        int col = n0 + wc*64 + nr*16 + llo;
        C[(size_t)row*CE + col] = acc[mr][nr][r] + bias[col];
      }
}

// ---------------- flash attention, T15 software pipeline ----------------
// Qp,Kp: [B*H, L, D] bf16 (Q pre-scaled by 0.125*log2e). Vt: [E, CM] bf16. Out AO [B,L,E] bf16.
// NEW (T15): per iteration, QK^T(t) MFMAs are issued FIRST, then softmax+PV of
// tile t-1 runs on the VALU while QK(t) drains the matrix pipe. S-tiles double-
// banked (sA/sB) with static indexing via 2x-unrolled pair loop (rule #20).
// Ring-4 already keeps K[t] and V[t-1] live simultaneously (distinct mod-4 slots).
// STAGE is issued AFTER the fused wait+barrier (WAITB("4"); STAGE(t+2)) so no
// gload_lds write can land in a buffer another wave is still reading.
// Ledger: entering iter t, {S(t),S(t+1)} = 8 outstanding; WAITB(4) confirms S(t);
// stage S(t+2) restores 8. Last iter waits 0.
__global__ __launch_bounds__(256,2) void attn_kernel(
    const u16* __restrict__ Qp, const u16* __restrict__ Kp, const u16* __restrict__ Vt,
    const float* __restrict__ maskf, u16* __restrict__ AO)
{
  __shared__ u16 K_lds[4][4096];   // ring of [kv64][d64] swizzled tiles
  __shared__ u16 V_lds[4][4096];   // ring of [d64][kv64] swizzled tiles
  __shared__ float M_lds[2048];    // padding mask row (exp2 domain) for this batch
  const int bh = blockIdx.x;
  const int slot = blockIdx.y;
  const int b = bh >> 4, h = bh & 15;
  const int tid=threadIdx.x, lane=tid&63, wid=tid>>6;
  const int l31 = lane&31, hi = lane>>5;
  const u16* Qh = Qp + (size_t)bh*CL*CD;
  const u16* Kh = Kp + (size_t)bh*CL*CD;
  const u16* Vhd = Vt + (size_t)(h*CD)*CM + b*CL;

  // stage padding-mask row once (8KB); confirmed by the first WAITB.
  #pragma unroll
  for (int i=0;i<2;i++)
    __builtin_amdgcn_global_load_lds(GP(maskf + b*CL + (i*256+tid)*4),
                                     LP(&M_lds[(i*256+tid)*4]), 16, 0, 0);

  auto STAGE = [&](int t, int buf){   // 4 gload_lds instructions per wave
    const u16* Ksrc = Kh + t*64*CD;
    const u16* Vsrc = Vhd + t*64;
    #pragma unroll
    for (int i=0;i<2;i++){
      int c = tid + i*256;
      int row = c>>3, sc = c&7;
      int c16 = sc ^ (row&7);
      __builtin_amdgcn_global_load_lds(GP(Ksrc + row*CD + c16*8),
                                       LP(&K_lds[buf][c*8]), 16, 0, 0);
      __builtin_amdgcn_global_load_lds(GP(Vsrc + (size_t)row*CM + c16*8),
                                       LP(&V_lds[buf][c*8]), 16, 0, 0);
    }
  };

  const int rowb = l31*128;            // LDS row byte base
  const int rsw  = (l31&7)<<4;
  const int qts2[2] = {15-slot, slot};

  for (int qi=0; qi<2; qi++){
    const int qt = qts2[qi];
    const int qw0 = qt*128 + wid*32;
    const int qlane = qw0 + l31;

    bf16x8 qf[4];
    #pragma unroll
    for (int c=0;c<4;c++)
      qf[c] = as_bf(*(const uint4*)(Qh + (size_t)qlane*CD + c*16 + hi*8));

    f32x16 o0 = {}, o1 = {};
    float m_r = -3e38f, l_r = 0.f;
    f32x16 sA0, sA1, sB0, sB1;         // double-banked S tiles

    const int nt = qt*2 + 2;
    STAGE(0,0); STAGE(1,1);

    // QK^T for tile t -> (d0,d1); Q carries 0.125*log2e
    auto QK = [&](int t, f32x16& d0, f32x16& d1){
      const char* kb = (const char*)K_lds[t&3];
      f32x16 z0 = {}, z1 = {};
      __builtin_amdgcn_s_setprio(1);
      #pragma unroll
      for (int c=0;c<4;c++){
        int cb = (c*32 + hi*16) ^ rsw;
        bf16x8 k0 = as_bf(*(const uint4*)(kb + rowb + cb));
        bf16x8 k1 = as_bf(*(const uint4*)(kb + 4096 + rowb + cb));
        z0 = __builtin_amdgcn_mfma_f32_32x32x16_bf16(k0, qf[c], z0, 0,0,0);
        z1 = __builtin_amdgcn_mfma_f32_32x32x16_bf16(k1, qf[c], z1, 0,0,0);
      }
      __builtin_amdgcn_s_setprio(0);
      d0 = z0; d1 = z1;
    };

    // softmax + PV for tile tp (S banks passed by ref; runs while QK(tp+1) drains)
    auto SMPV = [&](int tp, f32x16& s0, f32x16& s1){
      const int kv0 = tp*64;
      const char* vb = (const char*)V_lds[tp&3];

      // padding mask (broadcast LDS reads)
      f32x4 cm[8];
      #pragma unroll
      for (int s2=0;s2<2;s2++)
        #pragma unroll
        for (int g=0; g<4; g++)
          cm[s2*4+g] = *(const f32x4*)&M_lds[kv0 + s2*32 + g*8 + hi*4];

      // mask (+ causal on diagonal tiles), in place (exp2 domain)
      if (kv0 + 63 > qw0){
        #pragma unroll
        for (int s2=0;s2<2;s2++){
          f32x16& sv = s2 ? s1 : s0;
          #pragma unroll
          for (int reg=0; reg<16; reg++){
            int k = kv0 + s2*32 + (reg&3) + (reg>>2)*8 + hi*4;
            float v = sv[reg] + cm[s2*4+(reg>>2)][reg&3];
            sv[reg] = (k > qlane) ? v + NEGBIG : v;
          }
        }
      } else {
        #pragma unroll
        for (int s2=0;s2<2;s2++){
          f32x16& sv = s2 ? s1 : s0;
          #pragma unroll
          for (int reg=0; reg<16; reg++)
            sv[reg] = sv[reg] + cm[s2*4+(reg>>2)][reg&3];
        }
      }

      // row max
      f32x16 mx;
      #pragma unroll
      for (int r=0;r<16;r++) mx[r] = fmaxf(s0[r], s1[r]);
      float a0 = max3f(mx[0],mx[1],mx[2]);
      float a1 = max3f(mx[3],mx[4],mx[5]);
      float a2 = max3f(mx[6],mx[7],mx[8]);
      float a3 = max3f(mx[9],mx[10],mx[11]);
      float a4 = max3f(mx[12],mx[13],mx[14]);
      float vmax = fmaxf(max3f(a0,a1,a2), max3f(a3,a4,mx[15]));
      vmax = fmaxf(vmax, __shfl_xor(vmax, 32));

      // defer-max (T13)
      if (__any(vmax > m_r + 12.0f)){
        float mnew = fmaxf(m_r, vmax);
        float sc = fexp2(m_r - mnew);
        l_r *= sc;
        o0 *= sc; o1 *= sc;
        m_r = mnew;
      }

      // p = exp2(v - m)
      #pragma unroll
      for (int r=0;r<16;r++){
        s0[r] = fexp2(s0[r] - m_r);
        s1[r] = fexp2(s1[r] - m_r);
      }
      // row sum
      f32x16 sm = s0 + s1;
      #pragma unroll
      for (int w=8; w>=1; w>>=1)
        #pragma unroll
        for (int r=0;r<w;r++) sm[r] = sm[r] + sm[r+w];
      float rsum = sm[0];
      rsum += __shfl_xor(rsum, 32);
      l_r += rsum;

      // P -> bf16 B-fragments in-register
      u32 w_[16];
      #pragma unroll
      for (int s2=0;s2<2;s2++){
        f32x16& sv = s2 ? s1 : s0;
        #pragma unroll
        for (int c=0;c<2;c++){
          u32 a  = cvt_pk(sv[c*8+0], sv[c*8+1]);
          u32 bb = cvt_pk(sv[c*8+2], sv[c*8+3]);
          u32 cc = cvt_pk(sv[c*8+4], sv[c*8+5]);
          u32 dd = cvt_pk(sv[c*8+6], sv[c*8+7]);
          plswap(a, cc); plswap(bb, dd);
          int base = (s2*2+c)*4;
          w_[base+0]=a; w_[base+1]=bb; w_[base+2]=cc; w_[base+3]=dd;
        }
      }

      // O^T += V^T @ P^T
      __builtin_amdgcn_s_setprio(1);
      #pragma unroll
      for (int kc=0; kc<4; kc++){
        bf16x8 pf = as_bf(make_uint4(w_[kc*4], w_[kc*4+1], w_[kc*4+2], w_[kc*4+3]));
        int cb = (kc*32 + hi*16) ^ rsw;
        bf16x8 v0 = as_bf(*(const uint4*)(vb + rowb + cb));
        bf16x8 v1 = as_bf(*(const uint4*)(vb + 4096 + rowb + cb));
        o0 = __builtin_amdgcn_mfma_f32_32x32x16_bf16(v0, pf, o0, 0,0,0);
        o1 = __builtin_amdgcn_mfma_f32_32x32x16_bf16(v1, pf, o1, 0,0,0);
      }
      __builtin_amdgcn_s_setprio(0);
    };

    // t=0: QK only
    WAITB("4");                          // confirms S(0) (+mask, +qf)
    if (2 < nt) STAGE(2,2);
    QK(0, sA0, sA1);

    // pairs t=(2j+1, 2j+2), static S-bank parity
    #pragma unroll 1
    for (int jx=0; jx<qt; jx++){
      int t = 2*jx+1;                    // odd -> bank B
      WAITB("4");
      if (t+2 < nt) STAGE(t+2,(t+2)&3);
      QK(t, sB0, sB1);
      SMPV(t-1, sA0, sA1);
      t = 2*jx+2;                        // even -> bank A (never the last tile)
      WAITB("4");
      if (t+2 < nt) STAGE(t+2,(t+2)&3);
      QK(t, sA0, sA1);
      SMPV(t-1, sB0, sB1);
    }
    // t = nt-1 (odd)
    WAITB("0");
    QK(nt-1, sB0, sB1);
    SMPV(nt-2, sA0, sA1);
    // finish last tile
    SMPV(nt-1, sB0, sB1);

    // normalize + write O^T: lane has q=qlane, d = mt*32 + g*8 + hi*4 + {0..3}
    float inv = 1.f / l_r;
    u16* dst = AO + (size_t)(b*CL + qlane)*CE + h*CD;
    #pragma unroll
    for (int mt=0; mt<2; mt++){
      f32x16& ov = mt ? o1 : o0;
      #pragma unroll
      for (int g=0; g<4; g++){
        u32 lo  = cvt_pk(ov[g*4+0]*inv, ov[g*4+1]*inv);
        u32 hi2 = cvt_pk(ov[g*4+2]*inv, ov[g*4+3]*inv);
        *(uint2*)(dst + mt*32 + g*8 + hi*4) = make_uint2(lo, hi2);
      }
    }
    // protect ring reuse by qi=1 prologue (and reset vmcnt ledger)
    __syncthreads();
  }
}

// ---------------- launcher ----------------
extern "C" void kernel_launch(void* const* d_in, const int* in_sizes, int n_in,
                              void* d_out, int out_size, void* d_ws, size_t ws_size,
                              hipStream_t stream) {
  const float* query = (const float*)d_in[0];
  const float* key_  = (const float*)d_in[1];
  const float* value = (const float*)d_in[2];
  const float* wq = (const float*)d_in[3];
  const float* bq = (const float*)d_in[4];
  const float* wk = (const float*)d_in[5];
  const float* bk = (const float*)d_in[6];
  const float* wv = (const float*)d_in[7];
  const float* bv = (const float*)d_in[8];
  const float* wo = (const float*)d_in[9];
  const float* bo = (const float*)d_in[10];
  const void*  kpm = d_in[11];

  char* ws = (char*)d_ws;
  constexpr size_t SZ_ME_BF = (size_t)CM*CE*2;    // 16 MiB
  constexpr size_t OFF_MASKF= 256;
  constexpr size_t OFF_AO   = 65536;              // attn output, bf16 [B,L,E]
  constexpr size_t OFF_KP   = OFF_AO + SZ_ME_BF;
  constexpr size_t OFF_VT   = OFF_KP + SZ_ME_BF;  // Vt [1024][8192]
  constexpr size_t OFF_QP   = OFF_VT + SZ_ME_BF;

  float* maskf = (float*)(ws + OFF_MASKF);
  u16*  AO  = (u16*)(ws + OFF_AO);
  u16*  Kp  = (u16*)(ws + OFF_KP);
  u16*  Vt  = (u16*)(ws + OFF_VT);
  u16*  Qp  = (u16*)(ws + OFF_QP);

  mask_kernel<<<32,256,0,stream>>>(kpm, maskf);

  // projections read fp32 inputs directly (cast fused into staging) — no cast pass
  gemm_qkv<<<dim3(256,3),512,0,stream>>>(query, key_, value, wq, wk, wv,
                                         bq, bk, bv, Qp, Kp, Vt);

  attn_kernel<<<dim3(CB*CH, 8),256,0,stream>>>(Qp, Kp, Vt, maskf, AO);

  gemm_out<<<256,512,0,stream>>>(AO, wo, bo, (float*)d_out);
}

// Round 8
// 188.711 us; speedup vs baseline: 1.0210x; 1.0092x over previous
//
#include <hip/hip_runtime.h>

typedef unsigned short u16;
typedef unsigned int   u32;

using bf16x8 = __attribute__((ext_vector_type(8))) __bf16;
using f32x4  = __attribute__((ext_vector_type(4))) float;
using f32x16 = __attribute__((ext_vector_type(16))) float;
using u32x4  = __attribute__((ext_vector_type(4))) u32;

#define DEV static __device__ __forceinline__
#define GP(p) (const __attribute__((address_space(1))) void*)(p)
#define LP(p) (__attribute__((address_space(3))) void*)(p)
// fused counted-wait + barrier (T4)
#define WAITB(N) asm volatile("s_waitcnt vmcnt(" N ")\n\ts_barrier" ::: "memory")
// counted VMEM wait for reg-staged loads; sched_barrier pins register-only consumers (rule #18)
#define WAITVM(N) do{ asm volatile("s_waitcnt vmcnt(" N ")" ::: "memory"); \
                      __builtin_amdgcn_sched_barrier(0); }while(0)
// end-of-step: drain LDS ops then barrier
#define LGKMB asm volatile("s_waitcnt lgkmcnt(0)\n\ts_barrier" ::: "memory")

DEV u16 f2bf(float f){                      // RNE float->bf16
  u32 u = __builtin_bit_cast(u32, f);
  u32 r = u + 0x7fffu + ((u>>16)&1u);
  return (u16)(r>>16);
}
DEV float bcf(u32 x){ return __builtin_bit_cast(float, x); }
DEV bf16x8 as_bf(uint4 v){ return __builtin_bit_cast(bf16x8, v); }
DEV u32 cvt_pk(float lo, float hi){
  u32 r;
  asm("v_cvt_pk_bf16_f32 %0, %1, %2" : "=v"(r) : "v"(lo), "v"(hi));
  return r;
}
DEV void plswap(u32 &a, u32 &b){
  auto r = __builtin_amdgcn_permlane32_swap((int)a, (int)b, false, false);
  a = (u32)r[0]; b = (u32)r[1];
}
DEV float fexp2(float x){ float r; asm("v_exp_f32 %0, %1" : "=v"(r) : "v"(x)); return r; }
DEV float max3f(float a, float b, float c){
  float r; asm("v_max3_f32 %0, %1, %2, %3" : "=v"(r) : "v"(a), "v"(b), "v"(c)); return r;
}
DEV float fractf_(float x){ float r; asm("v_fract_f32 %0, %1" : "=v"(r) : "v"(x)); return r; }
DEV float sinrev(float f){ float r; asm("v_sin_f32 %0, %1" : "=v"(r) : "v"(f)); return r; }
DEV float cosrev(float f){ float r; asm("v_cos_f32 %0, %1" : "=v"(r) : "v"(f)); return r; }

// problem constants
constexpr int CB = 4, CL = 2048, CE = 1024, CH = 16, CD = 64;
constexpr int CM = CB*CL;           // 8192 rows
constexpr float LOG2E  = 1.44269504088896f;
constexpr float NEGBIG = -1.44269504e9f;    // -1e9 * log2e (exp2 domain)
constexpr float INV2PI = 0.15915494309189535f;

// ---------------- mask detect + convert, single launch ----------------
__global__ void mask_kernel(const void* __restrict__ mask, float* __restrict__ maskf){
  __shared__ int a_gt1, a_badf, a_oddnz, a_evennz;
  if (threadIdx.x==0){ a_gt1=0; a_badf=0; a_oddnz=0; a_evennz=0; }
  __syncthreads();
  const u32* w = (const u32*)mask;
  int gt1=0, badf=0, oddnz=0, evennz=0;
  for (int i=threadIdx.x; i<2048; i+=256){
    u32 v = w[i];
    if (v > 1u) gt1 = 1;
    if (v != 0u && v != 0x3f800000u) badf = 1;
    if (v != 0u){ if (i & 1) oddnz = 1; else evennz = 1; }
  }
  if (gt1) atomicOr(&a_gt1,1);
  if (badf) atomicOr(&a_badf,1);
  if (oddnz) atomicOr(&a_oddnz,1);
  if (evennz) atomicOr(&a_evennz,1);
  __syncthreads();
  int mode;
  if (!a_gt1)           mode = (!a_oddnz && a_evennz) ? 3 : 0;
  else if (!a_badf)     mode = 1;
  else                  mode = 2;
  int i = blockIdx.x*blockDim.x + threadIdx.x;   // B*L (grid covers exactly 8192)
  int v;
  if      (mode==0) v = ((const int*)mask)[i] != 0;
  else if (mode==1) v = ((const float*)mask)[i] != 0.f;
  else if (mode==3) v = ((const int*)mask)[2*i] != 0;
  else              v = ((const unsigned char*)mask)[i] != 0;
  maskf[i] = v ? NEGBIG : 0.f;
}

// ---------------- weights fp32 -> bf16 (wq, wk, wv only; ~18MB traffic ~3us) ----------------
__global__ void cast_w(const float* __restrict__ wq, const float* __restrict__ wk,
                       const float* __restrict__ wv,
                       u16* __restrict__ oq, u16* __restrict__ ok, u16* __restrict__ ov){
  int i = blockIdx.x*blockDim.x + threadIdx.x;   // 3 * 2^18 float4 items
  int w = i >> 18, j = i & ((1<<18)-1);
  const float* in = (w==0)?wq:(w==1)?wk:wv;
  u16* out = (w==0)?oq:(w==1)?ok:ov;
  float4 a = ((const float4*)in)[j];
  ushort4 h;
  h.x = f2bf(a.x); h.y = f2bf(a.y); h.z = f2bf(a.z); h.w = f2bf(a.w);
  ((ushort4*)out)[j] = h;
}

#define CVTW(dst, lo4, hi4) do{ \
  dst.x = cvt_pk(bcf(lo4.x), bcf(lo4.y)); \
  dst.y = cvt_pk(bcf(lo4.z), bcf(lo4.w)); \
  dst.z = cvt_pk(bcf(hi4.x), bcf(hi4.y)); \
  dst.w = cvt_pk(bcf(hi4.z), bcf(hi4.w)); \
}while(0)

// ---------------- QKV projection GEMM, hybrid staging ----------------
// 256x128 tile, 8 waves, BK=64. The narrow/reused operand travels as bf16 via
// global_load_lds (halves L2 re-read width); the wide operand stays fp32 and is
// reg-staged with cast-in-staging (R4 order, best measured).
//  z<2 : A = activation fp32 reg-staged (8 ld/thr), B = weight bf16 gload_lds ring-4
//        (2 ld/thr). Group=10, WAITVM(10) confirms tile t+1 (A regs + B in LDS).
//  z==2: A = wvb bf16 gload_lds ring-3 (4 ld/thr), B = value fp32 reg-staged
//        (4 ld/thr). Group=8, WAITVM(8). (= proven R4 gemm_out pipeline.)
// LDS 128KB carved per z. Banking: 128B rows, chunk ^= row&7 both sides (0 conflicts).
// z=0: Q = query@wq^T+bq, scaled 0.125*log2e, RoPE, pack [B,H,L,D]
// z=1: K = key@wk^T+bk, RoPE, pack [B,H,L,D]
// z=2: Vt = (wv@value^T)+bv[row], bf16 [E][CM] (pre-transposed V)
__global__ __launch_bounds__(512) void gemm_qkv(
    const float* __restrict__ query, const float* __restrict__ keyp,
    const float* __restrict__ value,
    const u16* __restrict__ wqb, const u16* __restrict__ wkb, const u16* __restrict__ wvb,
    const float* __restrict__ bq, const float* __restrict__ bk, const float* __restrict__ bv,
    u16* __restrict__ Qp, u16* __restrict__ Kp, u16* __restrict__ Vt)
{
  __shared__ u16 LDSU[65536];    // 128KB, carved per z
  const int z = blockIdx.y;
  const int tid=threadIdx.x, lane=tid&63, wid=tid>>6;
  const int llo=lane&15, lhi=lane>>4;
  int bid = blockIdx.x;                  // [0,256) per z
  int xcd = bid&7, j = bid>>3;           // j in [0,32)
  int mb, nb;
  if (z<2){ mb = xcd*4 + (j>>3); nb = j&7; }     // 32 x 8 tiles of 256x128
  else    { mb = j&3;  nb = xcd*8 + (j>>2); }    // 4 x 64 tiles (M=1024, N=8192)
  const int m0 = mb*256, n0 = nb*128;
  const int wr = wid>>1, wc = wid&1;     // 4M x 2N wave grid, 64x64 per wave
  const int rswA = llo&7;

  f32x4 acc[4][4] = {};

  auto COMP = [&](const u16* asrc, const u16* bsrc){
    const char* as = (const char*)asrc;
    const char* bs = (const char*)bsrc;
    #pragma unroll
    for (int ks=0; ks<2; ks++){
      bf16x8 af[4], bf_[4];
      #pragma unroll
      for (int mr=0;mr<4;mr++){
        int r = wr*64+mr*16+llo;
        af[mr] = as_bf(*(const uint4*)(as + r*128 + (((ks*4+lhi)^rswA)<<4)));
      }
      #pragma unroll
      for (int nr=0;nr<4;nr++){
        int r = wc*64+nr*16+llo;
        bf_[nr] = as_bf(*(const uint4*)(bs + r*128 + (((ks*4+lhi)^rswA)<<4)));
      }
      #pragma unroll
      for (int mr=0;mr<4;mr++)
        #pragma unroll
        for (int nr=0;nr<4;nr++)
          acc[mr][nr] = __builtin_amdgcn_mfma_f32_16x16x32_bf16(af[mr], bf_[nr], acc[mr][nr], 0,0,0);
    }
  };

  if (z < 2){
    const float* Af = z ? keyp : query;
    const u16*  Wb  = z ? wkb : wqb;
    u16* As0 = &LDSU[0];
    u16* As1 = &LDSU[16384];
    // B ring-4 slot s: &LDSU[32768 + s*8192]

    const float* aptr[4]; int aco[4];
    #pragma unroll
    for (int i=0;i<4;i++){
      int c = tid + i*512, row=c>>3, sc=(c&7)^(row&7);
      aptr[i] = Af + (size_t)(m0+row)*CE + sc*8;
      aco[i] = c*8;
    }
    u32x4 A0[8], A1[8];

#define LOADA(T, RA) do{ \
  _Pragma("unroll") \
  for (int i=0;i<4;i++){ \
    asm volatile("global_load_dwordx4 %0, %2, off\n\tglobal_load_dwordx4 %1, %2, off offset:16" \
      : "=&v"(RA[2*i]), "=&v"(RA[2*i+1]) : "v"(aptr[i] + (size_t)(T)*64) : "memory"); \
  } \
}while(0)

#define STAGEB(T, SLOT) do{ \
  _Pragma("unroll") \
  for (int i=0;i<2;i++){ \
    int c = tid + i*512, row=c>>3, sc=(c&7)^(row&7); \
    __builtin_amdgcn_global_load_lds(GP(Wb + (size_t)(n0+row)*CE + (T)*64 + sc*8), \
                                     LP(&LDSU[32768 + (SLOT)*8192 + c*8]), 16, 0, 0); \
  } \
}while(0)

#define WRITEA(DST, RA) do{ \
  _Pragma("unroll") \
  for (int i=0;i<4;i++){ \
    u32x4 w; CVTW(w, RA[2*i], RA[2*i+1]); \
    *(u32x4*)&DST[aco[i]] = w; \
  } \
}while(0)

    // prologue: groups 0,1 in flight (20); confirm tile0 (A regs + Bs slot0)
    LOADA(0, A0); STAGEB(0, 0);
    LOADA(1, A1); STAGEB(1, 1);
    WAITVM("10");
    WRITEA(As0, A0);
    LGKMB;

    #pragma unroll 1
    for (int jj=0; jj<7; jj++){
      const int t = 2*jj;
      LOADA(t+2, A0); STAGEB(t+2, (t+2)&3);
      WAITVM("10");                        // tile t+1 done (A1 regs + Bs[(t+1)&3])
      WRITEA(As1, A1);
      COMP(As0, &LDSU[32768 + (t&3)*8192]);
      LGKMB;
      LOADA(t+3, A1); STAGEB(t+3, (t+3)&3);
      WAITVM("10");                        // tile t+2 done
      WRITEA(As0, A0);
      COMP(As1, &LDSU[32768 + ((t+1)&3)*8192]);
      LGKMB;
    }
    // tiles 14,15 (group 15 still in flight)
    WAITVM("0");
    WRITEA(As1, A1);
    COMP(As0, &LDSU[32768 + 2*8192]);      // t=14, slot 2
    LGKMB;
    COMP(As1, &LDSU[32768 + 3*8192]);      // t=15, slot 3

#undef LOADA
#undef STAGEB
#undef WRITEA

    // ---- epilogue: bias + scale + RoPE + pack [B,H,L,D]
    const int colbase = n0 + wc*64;
    const float* bias = z ? bk : bq;
    u16* outp = z ? Kp : Qp;
    const float scale = z ? 1.f : 0.125f*LOG2E;
    const int h = colbase >> 6;           // wave covers exactly one head
    float b1[2], b2[2], invr[2];
    #pragma unroll
    for (int nr=0;nr<2;nr++){
      int j2 = nr*16 + llo;
      b1[nr] = bias[colbase + j2];
      b2[nr] = bias[colbase + j2 + 32];
      invr[nr] = exp2f(-(float)j2 * 0.41524101186092033f) * INV2PI;  // 10000^{-j2/32}/(2pi)
    }
    #pragma unroll
    for (int mr=0;mr<4;mr++)
      #pragma unroll
      for (int r=0;r<4;r++){
        int row = m0 + wr*64 + mr*16 + lhi*4 + r;
        int b = row >> 11, l = row & 2047;
        u16* dst = outp + (((size_t)(b*CH + h)*CL + l) << 6);
        #pragma unroll
        for (int nr=0;nr<2;nr++){
          int j2 = nr*16 + llo;
          float x1 = (acc[mr][nr][r]   + b1[nr]) * scale;
          float x2 = (acc[mr][nr+2][r] + b2[nr]) * scale;
          float fr = fractf_((float)l * invr[nr]);
          float sn = sinrev(fr), cs = cosrev(fr);
          dst[j2]      = f2bf(x1*cs - x2*sn);
          dst[j2 + 32] = f2bf(x2*cs + x1*sn);
        }
      }
  } else {
    // z==2: A = wvb bf16 gload_lds ring-3, B = value fp32 reg-staged (R4 gemm_out pipeline)
    // As slot s: &LDSU[s*16384]; Bs bufs: &LDSU[49152], &LDSU[57344]
    u16* Bs0 = &LDSU[49152];
    u16* Bs1 = &LDSU[57344];

    const float* bptr[2]; int bco[2];
    #pragma unroll
    for (int i=0;i<2;i++){
      int c = tid + i*512, row=c>>3, sc=(c&7)^(row&7);
      bptr[i] = value + (size_t)(n0+row)*CE + sc*8;
      bco[i] = c*8;
    }
    u32x4 B0[4], B1[4];

#define STAGEA(T, SLOT) do{ \
  _Pragma("unroll") \
  for (int i=0;i<4;i++){ \
    int c = tid + i*512, row=c>>3, sc=(c&7)^(row&7); \
    __builtin_amdgcn_global_load_lds(GP(wvb + (size_t)(m0+row)*CE + (T)*64 + sc*8), \
                                     LP(&LDSU[(SLOT)*16384 + c*8]), 16, 0, 0); \
  } \
}while(0)

#define LOADB(T, RB) do{ \
  _Pragma("unroll") \
  for (int i=0;i<2;i++){ \
    asm volatile("global_load_dwordx4 %0, %2, off\n\tglobal_load_dwordx4 %1, %2, off offset:16" \
      : "=&v"(RB[2*i]), "=&v"(RB[2*i+1]) : "v"(bptr[i] + (size_t)(T)*64) : "memory"); \
  } \
}while(0)

#define WRITEB(DST, RB) do{ \
  _Pragma("unroll") \
  for (int i=0;i<2;i++){ \
    u32x4 w; CVTW(w, RB[2*i], RB[2*i+1]); \
    *(u32x4*)&DST[bco[i]] = w; \
  } \
}while(0)

    STAGEA(0,0); LOADB(0, B0);
    STAGEA(1,1); LOADB(1, B1);
    WAITVM("8");
    WRITEB(Bs0, B0);
    LGKMB;

    #pragma unroll 1
    for (int jj=0; jj<7; jj++){
      const int t = 2*jj;
      STAGEA(t+2, (t+2)%3); LOADB(t+2, B0);
      WAITVM("8");
      WRITEB(Bs1, B1);
      COMP(&LDSU[(t%3)*16384], Bs0);
      LGKMB;
      STAGEA(t+3, (t+3)%3); LOADB(t+3, B1);
      WAITVM("8");
      WRITEB(Bs0, B0);
      COMP(&LDSU[((t+1)%3)*16384], Bs1);
      LGKMB;
    }
    WAITVM("0");
    WRITEB(Bs1, B1);
    COMP(&LDSU[(14%3)*16384], Bs0);        // t=14, slot 2
    LGKMB;
    COMP(&LDSU[(15%3)*16384], Bs1);        // t=15, slot 0

#undef STAGEA
#undef LOADB
#undef WRITEB

    // ---- epilogue: bias per row, write Vt [E][CM]
    const int colbase = n0 + wc*64;
    #pragma unroll
    for (int mr=0;mr<4;mr++)
      #pragma unroll
      for (int r=0;r<4;r++){
        int row = m0 + wr*64 + mr*16 + lhi*4 + r;
        float bvv = bv[row];
        #pragma unroll
        for (int nr=0;nr<4;nr++){
          int col = colbase + nr*16 + llo;
          Vt[(size_t)row*CM + col] = f2bf(acc[mr][nr][r] + bvv);
        }
      }
  }
}

// ---------------- output projection GEMM (fp32 out, bias per col) ----------------
// A = AO bf16 via global_load_lds ring-3; B = wo fp32 reg-staged (cast in staging).
__global__ __launch_bounds__(512) void gemm_out(
    const u16* __restrict__ A, const float* __restrict__ Btf,
    const float* __restrict__ bias, float* __restrict__ C)
{
  __shared__ u16 As[3][16384];   // 48KB
  __shared__ u16 Bs[2][8192];    // 32KB
  const int tid=threadIdx.x, lane=tid&63, wid=tid>>6;
  const int llo=lane&15, lhi=lane>>4;
  int bid = blockIdx.x;
  int xcd = bid&7, j = bid>>3;
  const int m0 = (xcd*4 + (j>>3))*256, n0 = (j&7)*128;   // 32 x 8 tiles of 256x128
  const int wr = wid>>1, wc = wid&1;
  const int rswA = llo&7;

  auto STAGEA = [&](int t, int buf){     // 4 gload_lds / thread
    #pragma unroll
    for (int i=0;i<4;i++){
      int c = tid + i*512, row=c>>3, sc=(c&7)^(row&7);
      __builtin_amdgcn_global_load_lds(GP(A + (size_t)(m0+row)*CE + t*64 + sc*8),
                                       LP(&As[buf][c*8]), 16, 0, 0);
    }
  };

  const float* bptr[2]; int bco[2];
  #pragma unroll
  for (int i=0;i<2;i++){
    int c = tid + i*512, row=c>>3, sc=(c&7)^(row&7);
    bptr[i] = Btf + (size_t)(n0+row)*CE + sc*8;
    bco[i] = c*8;
  }
  u32x4 B0[4], B1[4];

#define LOADB(T, RB) do{ \
  _Pragma("unroll") \
  for (int i=0;i<2;i++){ \
    asm volatile("global_load_dwordx4 %0, %2, off\n\tglobal_load_dwordx4 %1, %2, off offset:16" \
      : "=&v"(RB[2*i]), "=&v"(RB[2*i+1]) : "v"(bptr[i] + (size_t)(T)*64) : "memory"); \
  } \
}while(0)

#define WRITEB(BUF, RB) do{ \
  _Pragma("unroll") \
  for (int i=0;i<2;i++){ \
    u32x4 w; CVTW(w, RB[2*i], RB[2*i+1]); \
    *(u32x4*)&Bs[BUF][bco[i]] = w; \
  } \
}while(0)

  f32x4 acc[4][4] = {};

  auto COMP = [&](int abuf, int bbuf){
    const char* as = (const char*)As[abuf];
    const char* bs = (const char*)Bs[bbuf];
    #pragma unroll
    for (int ks=0; ks<2; ks++){
      bf16x8 af[4], bf_[4];
      #pragma unroll
      for (int mr=0;mr<4;mr++){
        int r = wr*64+mr*16+llo;
        af[mr] = as_bf(*(const uint4*)(as + r*128 + (((ks*4+lhi)^rswA)<<4)));
      }
      #pragma unroll
      for (int nr=0;nr<4;nr++){
        int r = wc*64+nr*16+llo;
        bf_[nr] = as_bf(*(const uint4*)(bs + r*128 + (((ks*4+lhi)^rswA)<<4)));
      }
      #pragma unroll
      for (int mr=0;mr<4;mr++)
        #pragma unroll
        for (int nr=0;nr<4;nr++)
          acc[mr][nr] = __builtin_amdgcn_mfma_f32_16x16x32_bf16(af[mr], bf_[nr], acc[mr][nr], 0,0,0);
    }
  };

  // prologue: A(0),B(0),A(1),B(1) in flight; confirm tile0 pair, write B0
  STAGEA(0,0); LOADB(0, B0);
  STAGEA(1,1); LOADB(1, B1);
  WAITVM("8");
  WRITEB(0, B0);
  LGKMB;

  #pragma unroll 1
  for (int jj=0; jj<7; jj++){
    const int t = 2*jj;
    STAGEA(t+2, (t+2)%3); LOADB(t+2, B0);
    WAITVM("8");
    WRITEB(1, B1);
    COMP(t%3, 0);
    LGKMB;
    STAGEA(t+3, (t+3)%3); LOADB(t+3, B1);
    WAITVM("8");
    WRITEB(0, B0);
    COMP((t+1)%3, 1);
    LGKMB;
  }
  WAITVM("0");
  WRITEB(1, B1);
  COMP(2, 0);          // t=14
  LGKMB;
  COMP(0, 1);          // t=15

#undef LOADB
#undef WRITEB

  #pragma unroll
  for (int mr=0;mr<4;mr++)
    #pragma unroll
    for (int nr=0;nr<4;nr++)
      #pragma unroll
      for (int r=0;r<4;r++){
        int row = m0 + wr*64 + mr*16 + lhi*4 + r;
        int col = n0 + wc*64 + nr*16 + llo;
        C[(size_t)row*CE + col] = acc[mr][nr][r] + bias[col];
      }
}

// ---------------- flash attention, T15 software pipeline ----------------
// Qp,Kp: [B*H, L, D] bf16 (Q pre-scaled by 0.125*log2e). Vt: [E, CM] bf16. Out AO [B,L,E] bf16.
__global__ __launch_bounds__(256,2) void attn_kernel(
    const u16* __restrict__ Qp, const u16* __restrict__ Kp, const u16* __restrict__ Vt,
    const float* __restrict__ maskf, u16* __restrict__ AO)
{
  __shared__ u16 K_lds[4][4096];   // ring of [kv64][d64] swizzled tiles
  __shared__ u16 V_lds[4][4096];   // ring of [d64][kv64] swizzled tiles
  __shared__ float M_lds[2048];    // padding mask row (exp2 domain) for this batch
  const int bh = blockIdx.x;
  const int slot = blockIdx.y;
  const int b = bh >> 4, h = bh & 15;
  const int tid=threadIdx.x, lane=tid&63, wid=tid>>6;
  const int l31 = lane&31, hi = lane>>5;
  const u16* Qh = Qp + (size_t)bh*CL*CD;
  const u16* Kh = Kp + (size_t)bh*CL*CD;
  const u16* Vhd = Vt + (size_t)(h*CD)*CM + b*CL;

  // stage padding-mask row once (8KB); confirmed by the first WAITB.
  #pragma unroll
  for (int i=0;i<2;i++)
    __builtin_amdgcn_global_load_lds(GP(maskf + b*CL + (i*256+tid)*4),
                                     LP(&M_lds[(i*256+tid)*4]), 16, 0, 0);

  auto STAGE = [&](int t, int buf){   // 4 gload_lds instructions per wave
    const u16* Ksrc = Kh + t*64*CD;
    const u16* Vsrc = Vhd + t*64;
    #pragma unroll
    for (int i=0;i<2;i++){
      int c = tid + i*256;
      int row = c>>3, sc = c&7;
      int c16 = sc ^ (row&7);
      __builtin_amdgcn_global_load_lds(GP(Ksrc + row*CD + c16*8),
                                       LP(&K_lds[buf][c*8]), 16, 0, 0);
      __builtin_amdgcn_global_load_lds(GP(Vsrc + (size_t)row*CM + c16*8),
                                       LP(&V_lds[buf][c*8]), 16, 0, 0);
    }
  };

  const int rowb = l31*128;            // LDS row byte base
  const int rsw  = (l31&7)<<4;
  const int qts2[2] = {15-slot, slot};

  for (int qi=0; qi<2; qi++){
    const int qt = qts2[qi];
    const int qw0 = qt*128 + wid*32;
    const int qlane = qw0 + l31;

    bf16x8 qf[4];
    #pragma unroll
    for (int c=0;c<4;c++)
      qf[c] = as_bf(*(const uint4*)(Qh + (size_t)qlane*CD + c*16 + hi*8));

    f32x16 o0 = {}, o1 = {};
    float m_r = -3e38f, l_r = 0.f;
    f32x16 sA0, sA1, sB0, sB1;         // double-banked S tiles

    const int nt = qt*2 + 2;
    STAGE(0,0); STAGE(1,1);

    // QK^T for tile t -> (d0,d1); Q carries 0.125*log2e
    auto QK = [&](int t, f32x16& d0, f32x16& d1){
      const char* kb = (const char*)K_lds[t&3];
      f32x16 z0 = {}, z1 = {};
      __builtin_amdgcn_s_setprio(1);
      #pragma unroll
      for (int c=0;c<4;c++){
        int cb = (c*32 + hi*16) ^ rsw;
        bf16x8 k0 = as_bf(*(const uint4*)(kb + rowb + cb));
        bf16x8 k1 = as_bf(*(const uint4*)(kb + 4096 + rowb + cb));
        z0 = __builtin_amdgcn_mfma_f32_32x32x16_bf16(k0, qf[c], z0, 0,0,0);
        z1 = __builtin_amdgcn_mfma_f32_32x32x16_bf16(k1, qf[c], z1, 0,0,0);
      }
      __builtin_amdgcn_s_setprio(0);
      d0 = z0; d1 = z1;
    };

    // softmax + PV for tile tp (S banks passed by ref; runs while QK(tp+1) drains)
    auto SMPV = [&](int tp, f32x16& s0, f32x16& s1){
      const int kv0 = tp*64;
      const char* vb = (const char*)V_lds[tp&3];

      // padding mask (broadcast LDS reads)
      f32x4 cm[8];
      #pragma unroll
      for (int s2=0;s2<2;s2++)
        #pragma unroll
        for (int g=0; g<4; g++)
          cm[s2*4+g] = *(const f32x4*)&M_lds[kv0 + s2*32 + g*8 + hi*4];

      // mask (+ causal on diagonal tiles), in place (exp2 domain)
      if (kv0 + 63 > qw0){
        #pragma unroll
        for (int s2=0;s2<2;s2++){
          f32x16& sv = s2 ? s1 : s0;
          #pragma unroll
          for (int reg=0; reg<16; reg++){
            int k = kv0 + s2*32 + (reg&3) + (reg>>2)*8 + hi*4;
            float v = sv[reg] + cm[s2*4+(reg>>2)][reg&3];
            sv[reg] = (k > qlane) ? v + NEGBIG : v;
          }
        }
      } else {
        #pragma unroll
        for (int s2=0;s2<2;s2++){
          f32x16& sv = s2 ? s1 : s0;
          #pragma unroll
          for (int reg=0; reg<16; reg++)
            sv[reg] = sv[reg] + cm[s2*4+(reg>>2)][reg&3];
        }
      }

      // row max
      f32x16 mx;
      #pragma unroll
      for (int r=0;r<16;r++) mx[r] = fmaxf(s0[r], s1[r]);
      float a0 = max3f(mx[0],mx[1],mx[2]);
      float a1 = max3f(mx[3],mx[4],mx[5]);
      float a2 = max3f(mx[6],mx[7],mx[8]);
      float a3 = max3f(mx[9],mx[10],mx[11]);
      float a4 = max3f(mx[12],mx[13],mx[14]);
      float vmax = fmaxf(max3f(a0,a1,a2), max3f(a3,a4,mx[15]));
      vmax = fmaxf(vmax, __shfl_xor(vmax, 32));

      // defer-max (T13)
      if (__any(vmax > m_r + 12.0f)){
        float mnew = fmaxf(m_r, vmax);
        float sc = fexp2(m_r - mnew);
        l_r *= sc;
        o0 *= sc; o1 *= sc;
        m_r = mnew;
      }

      // p = exp2(v - m)
      #pragma unroll
      for (int r=0;r<16;r++){
        s0[r] = fexp2(s0[r] - m_r);
        s1[r] = fexp2(s1[r] - m_r);
      }
      // row sum
      f32x16 sm = s0 + s1;
      #pragma unroll
      for (int w=8; w>=1; w>>=1)
        #pragma unroll
        for (int r=0;r<w;r++) sm[r] = sm[r] + sm[r+w];
      float rsum = sm[0];
      rsum += __shfl_xor(rsum, 32);
      l_r += rsum;

      // P -> bf16 B-fragments in-register
      u32 w_[16];
      #pragma unroll
      for (int s2=0;s2<2;s2++){
        f32x16& sv = s2 ? s1 : s0;
        #pragma unroll
        for (int c=0;c<2;c++){
          u32 a  = cvt_pk(sv[c*8+0], sv[c*8+1]);
          u32 bb = cvt_pk(sv[c*8+2], sv[c*8+3]);
          u32 cc = cvt_pk(sv[c*8+4], sv[c*8+5]);
          u32 dd = cvt_pk(sv[c*8+6], sv[c*8+7]);
          plswap(a, cc); plswap(bb, dd);
          int base = (s2*2+c)*4;
          w_[base+0]=a; w_[base+1]=bb; w_[base+2]=cc; w_[base+3]=dd;
        }
      }

      // O^T += V^T @ P^T
      __builtin_amdgcn_s_setprio(1);
      #pragma unroll
      for (int kc=0; kc<4; kc++){
        bf16x8 pf = as_bf(make_uint4(w_[kc*4], w_[kc*4+1], w_[kc*4+2], w_[kc*4+3]));
        int cb = (kc*32 + hi*16) ^ rsw;
        bf16x8 v0 = as_bf(*(const uint4*)(vb + rowb + cb));
        bf16x8 v1 = as_bf(*(const uint4*)(vb + 4096 + rowb + cb));
        o0 = __builtin_amdgcn_mfma_f32_32x32x16_bf16(v0, pf, o0, 0,0,0);
        o1 = __builtin_amdgcn_mfma_f32_32x32x16_bf16(v1, pf, o1, 0,0,0);
      }
      __builtin_amdgcn_s_setprio(0);
    };

    // t=0: QK only
    WAITB("4");                          // confirms S(0) (+mask, +qf)
    if (2 < nt) STAGE(2,2);
    QK(0, sA0, sA1);

    // pairs t=(2j+1, 2j+2), static S-bank parity
    #pragma unroll 1
    for (int jx=0; jx<qt; jx++){
      int t = 2*jx+1;                    // odd -> bank B
      WAITB("4");
      if (t+2 < nt) STAGE(t+2,(t+2)&3);
      QK(t, sB0, sB1);
      SMPV(t-1, sA0, sA1);
      t = 2*jx+2;                        // even -> bank A (never the last tile)
      WAITB("4");
      if (t+2 < nt) STAGE(t+2,(t+2)&3);
      QK(t, sA0, sA1);
      SMPV(t-1, sB0, sB1);
    }
    // t = nt-1 (odd)
    WAITB("0");
    QK(nt-1, sB0, sB1);
    SMPV(nt-2, sA0, sA1);
    // finish last tile
    SMPV(nt-1, sB0, sB1);

    // normalize + write O^T: lane has q=qlane, d = mt*32 + g*8 + hi*4 + {0..3}
    float inv = 1.f / l_r;
    u16* dst = AO + (size_t)(b*CL + qlane)*CE + h*CD;
    #pragma unroll
    for (int mt=0; mt<2; mt++){
      f32x16& ov = mt ? o1 : o0;
      #pragma unroll
      for (int g=0; g<4; g++){
        u32 lo  = cvt_pk(ov[g*4+0]*inv, ov[g*4+1]*inv);
        u32 hi2 = cvt_pk(ov[g*4+2]*inv, ov[g*4+3]*inv);
        *(uint2*)(dst + mt*32 + g*8 + hi*4) = make_uint2(lo, hi2);
      }
    }
    // protect ring reuse by qi=1 prologue (and reset vmcnt ledger)
    __syncthreads();
  }
}

// ---------------- launcher ----------------
extern "C" void kernel_launch(void* const* d_in, const int* in_sizes, int n_in,
                              void* d_out, int out_size, void* d_ws, size_t ws_size,
                              hipStream_t stream) {
  const float* query = (const float*)d_in[0];
  const float* key_  = (const float*)d_in[1];
  const float* value = (const float*)d_in[2];
  const float* wq = (const float*)d_in[3];
  const float* bq = (const float*)d_in[4];
  const float* wk = (const float*)d_in[5];
  const float* bk = (const float*)d_in[6];
  const float* wv = (const float*)d_in[7];
  const float* bv = (const float*)d_in[8];
  const float* wo = (const float*)d_in[9];
  const float* bo = (const float*)d_in[10];
  const void*  kpm = d_in[11];

  char* ws = (char*)d_ws;
  constexpr size_t SZ_ME_BF = (size_t)CM*CE*2;    // 16 MiB
  constexpr size_t OFF_MASKF= 256;
  constexpr size_t OFF_AO   = 65536;              // attn output, bf16 [B,L,E]
  constexpr size_t OFF_KP   = OFF_AO + SZ_ME_BF;
  constexpr size_t OFF_VT   = OFF_KP + SZ_ME_BF;  // Vt [1024][8192]
  constexpr size_t OFF_QP   = OFF_VT + SZ_ME_BF;

  float* maskf = (float*)(ws + OFF_MASKF);
  u16*  AO  = (u16*)(ws + OFF_AO);
  u16*  Kp  = (u16*)(ws + OFF_KP);
  u16*  Vt  = (u16*)(ws + OFF_VT);
  u16*  Qp  = (u16*)(ws + OFF_QP);

  // bf16 weights live in the head of AO: dead until attn writes AO (stream-ordered,
  // gemm_qkv completes before attn starts). 3 x 1M u16 = 6MB < 16MB.
  u16* wqb = AO;
  u16* wkb = AO + (size_t)CE*CE;
  u16* wvb = AO + (size_t)2*CE*CE;

  mask_kernel<<<32,256,0,stream>>>(kpm, maskf);
  cast_w<<<3072,256,0,stream>>>(wq, wk, wv, wqb, wkb, wvb);

  gemm_qkv<<<dim3(256,3),512,0,stream>>>(query, key_, value, wqb, wkb, wvb,
                                         bq, bk, bv, Qp, Kp, Vt);

  attn_kernel<<<dim3(CB*CH, 8),256,0,stream>>>(Qp, Kp, Vt, maskf, AO);

  gemm_out<<<256,512,0,stream>>>(AO, wo, bo, (float*)d_out);
}

// Round 10
// 180.958 us; speedup vs baseline: 1.0647x; 1.0428x over previous
//
#include <hip/hip_runtime.h>

typedef unsigned short u16;
typedef unsigned int   u32;

using bf16x8 = __attribute__((ext_vector_type(8))) __bf16;
using f32x4  = __attribute__((ext_vector_type(4))) float;
using f32x16 = __attribute__((ext_vector_type(16))) float;
using u32x4  = __attribute__((ext_vector_type(4))) u32;

#define DEV static __device__ __forceinline__
#define GP(p) (const __attribute__((address_space(1))) void*)(p)
#define LP(p) (__attribute__((address_space(3))) void*)(p)
// fused counted-wait + barrier (T4)
#define WAITB(N) asm volatile("s_waitcnt vmcnt(" N ")\n\ts_barrier" ::: "memory")
// counted VMEM wait for reg-staged loads; sched_barrier pins register-only consumers (rule #18)
#define WAITVM(N) do{ asm volatile("s_waitcnt vmcnt(" N ")" ::: "memory"); \
                      __builtin_amdgcn_sched_barrier(0); }while(0)
// end-of-step: drain LDS ops then barrier
#define LGKMB asm volatile("s_waitcnt lgkmcnt(0)\n\ts_barrier" ::: "memory")

DEV u16 f2bf(float f){                      // RNE float->bf16
  u32 u = __builtin_bit_cast(u32, f);
  u32 r = u + 0x7fffu + ((u>>16)&1u);
  return (u16)(r>>16);
}
DEV float bcf(u32 x){ return __builtin_bit_cast(float, x); }
DEV bf16x8 as_bf(uint4 v){ return __builtin_bit_cast(bf16x8, v); }
DEV u32 cvt_pk(float lo, float hi){
  u32 r;
  asm("v_cvt_pk_bf16_f32 %0, %1, %2" : "=v"(r) : "v"(lo), "v"(hi));
  return r;
}
DEV void plswap(u32 &a, u32 &b){
  auto r = __builtin_amdgcn_permlane32_swap((int)a, (int)b, false, false);
  a = (u32)r[0]; b = (u32)r[1];
}
DEV float fexp2(float x){ float r; asm("v_exp_f32 %0, %1" : "=v"(r) : "v"(x)); return r; }
DEV float max3f(float a, float b, float c){
  float r; asm("v_max3_f32 %0, %1, %2, %3" : "=v"(r) : "v"(a), "v"(b), "v"(c)); return r;
}
DEV float fractf_(float x){ float r; asm("v_fract_f32 %0, %1" : "=v"(r) : "v"(x)); return r; }
DEV float sinrev(float f){ float r; asm("v_sin_f32 %0, %1" : "=v"(r) : "v"(f)); return r; }
DEV float cosrev(float f){ float r; asm("v_cos_f32 %0, %1" : "=v"(r) : "v"(f)); return r; }

// problem constants
constexpr int CB = 4, CL = 2048, CE = 1024, CH = 16, CD = 64;
constexpr int CM = CB*CL;           // 8192 rows
constexpr float LOG2E  = 1.44269504088896f;
constexpr float NEGBIG = -1.44269504e9f;    // -1e9 * log2e (exp2 domain)
constexpr float INV2PI = 0.15915494309189535f;

// ---------------- mask detect+convert AND weight cast, one launch ----------------
// blocks [0,3072): cast wq/wk/wv fp32->bf16 (3*2^18 float4 items)
// blocks [3072,3104): mask detect + convert (32 blocks x 256 = 8192 entries)
__global__ void prep_kernel(const float* __restrict__ wq, const float* __restrict__ wk,
                            const float* __restrict__ wv,
                            u16* __restrict__ oq, u16* __restrict__ ok, u16* __restrict__ ov,
                            const void* __restrict__ mask, float* __restrict__ maskf){
  if (blockIdx.x < 3072){
    int i = blockIdx.x*blockDim.x + threadIdx.x;
    int w = i >> 18, j = i & ((1<<18)-1);
    const float* in = (w==0)?wq:(w==1)?wk:wv;
    u16* out = (w==0)?oq:(w==1)?ok:ov;
    float4 a = ((const float4*)in)[j];
    ushort4 h;
    h.x = f2bf(a.x); h.y = f2bf(a.y); h.z = f2bf(a.z); h.w = f2bf(a.w);
    ((ushort4*)out)[j] = h;
    return;
  }
  __shared__ int a_gt1, a_badf, a_oddnz, a_evennz;
  if (threadIdx.x==0){ a_gt1=0; a_badf=0; a_oddnz=0; a_evennz=0; }
  __syncthreads();
  const u32* w = (const u32*)mask;
  int gt1=0, badf=0, oddnz=0, evennz=0;
  for (int i=threadIdx.x; i<2048; i+=256){
    u32 v = w[i];
    if (v > 1u) gt1 = 1;
    if (v != 0u && v != 0x3f800000u) badf = 1;
    if (v != 0u){ if (i & 1) oddnz = 1; else evennz = 1; }
  }
  if (gt1) atomicOr(&a_gt1,1);
  if (badf) atomicOr(&a_badf,1);
  if (oddnz) atomicOr(&a_oddnz,1);
  if (evennz) atomicOr(&a_evennz,1);
  __syncthreads();
  int mode;
  if (!a_gt1)           mode = (!a_oddnz && a_evennz) ? 3 : 0;
  else if (!a_badf)     mode = 1;
  else                  mode = 2;
  int i = (blockIdx.x-3072)*blockDim.x + threadIdx.x;   // B*L
  int v;
  if      (mode==0) v = ((const int*)mask)[i] != 0;
  else if (mode==1) v = ((const float*)mask)[i] != 0.f;
  else if (mode==3) v = ((const int*)mask)[2*i] != 0;
  else              v = ((const unsigned char*)mask)[i] != 0;
  maskf[i] = v ? NEGBIG : 0.f;
}

#define CVTW(dst, lo4, hi4) do{ \
  dst.x = cvt_pk(bcf(lo4.x), bcf(lo4.y)); \
  dst.y = cvt_pk(bcf(lo4.z), bcf(lo4.w)); \
  dst.z = cvt_pk(bcf(hi4.x), bcf(hi4.y)); \
  dst.w = cvt_pk(bcf(hi4.z), bcf(hi4.w)); \
}while(0)

// ---------------- QKV projection GEMM, hybrid staging + TRIPLE reg sets ----------------
// 256x128 tile, 8 waves, BK=64. Reused operand = bf16 via global_load_lds; streamed
// operand = fp32 reg-staged with cast-in-staging. 3 rotating reg sets so the
// fp32 stream's load is issued TWO steps before its confirming wait (2 steps ~
// 800-1000cyc >= HBM latency), with issues ordered (lds-op, reg-op) so the FIFO
// wait never force-confirms a young reg set. vmcnt ledgers hand-traced per step.
//  z<2 : A = activation fp32 reg-staged (8 ld/thr, sets S0/S1/S2),
//        B = weight bf16 gload_lds ring-4 (2 ld/thr).
//  z==2: A = wvb bf16 gload_lds ring-3 (4 ld/thr),
//        B = value fp32 reg-staged (4 ld/thr, sets R0/R1/R2).
// LDS 128KB carved per z. Banking: 128B rows, chunk ^= row&7 both sides (0 conflicts).
__global__ __launch_bounds__(512) void gemm_qkv(
    const float* __restrict__ query, const float* __restrict__ keyp,
    const float* __restrict__ value,
    const u16* __restrict__ wqb, const u16* __restrict__ wkb, const u16* __restrict__ wvb,
    const float* __restrict__ bq, const float* __restrict__ bk, const float* __restrict__ bv,
    u16* __restrict__ Qp, u16* __restrict__ Kp, u16* __restrict__ Vt)
{
  __shared__ u16 LDSU[65536];    // 128KB, carved per z
  const int z = blockIdx.y;
  const int tid=threadIdx.x, lane=tid&63, wid=tid>>6;
  const int llo=lane&15, lhi=lane>>4;
  int bid = blockIdx.x;                  // [0,256) per z
  int xcd = bid&7, j = bid>>3;           // j in [0,32)
  int mb, nb;
  if (z<2){ mb = xcd*4 + (j>>3); nb = j&7; }     // 32 x 8 tiles of 256x128
  else    { mb = j&3;  nb = xcd*8 + (j>>2); }    // 4 x 64 tiles (M=1024, N=8192)
  const int m0 = mb*256, n0 = nb*128;
  const int wr = wid>>1, wc = wid&1;     // 4M x 2N wave grid, 64x64 per wave
  const int rswA = llo&7;

  f32x4 acc[4][4] = {};

  auto COMP = [&](const u16* asrc, const u16* bsrc){
    const char* as = (const char*)asrc;
    const char* bs = (const char*)bsrc;
    #pragma unroll
    for (int ks=0; ks<2; ks++){
      bf16x8 af[4], bf_[4];
      #pragma unroll
      for (int mr=0;mr<4;mr++){
        int r = wr*64+mr*16+llo;
        af[mr] = as_bf(*(const uint4*)(as + r*128 + (((ks*4+lhi)^rswA)<<4)));
      }
      #pragma unroll
      for (int nr=0;nr<4;nr++){
        int r = wc*64+nr*16+llo;
        bf_[nr] = as_bf(*(const uint4*)(bs + r*128 + (((ks*4+lhi)^rswA)<<4)));
      }
      #pragma unroll
      for (int mr=0;mr<4;mr++)
        #pragma unroll
        for (int nr=0;nr<4;nr++)
          acc[mr][nr] = __builtin_amdgcn_mfma_f32_16x16x32_bf16(af[mr], bf_[nr], acc[mr][nr], 0,0,0);
    }
  };

  if (z < 2){
    const float* Af = z ? keyp : query;
    const u16*  Wb  = z ? wkb : wqb;
    u16* As0 = &LDSU[0];
    u16* As1 = &LDSU[16384];
    // B ring-4 slot s: &LDSU[32768 + s*8192]

    const float* aptr[4]; int aco[4];
    #pragma unroll
    for (int i=0;i<4;i++){
      int c = tid + i*512, row=c>>3, sc=(c&7)^(row&7);
      aptr[i] = Af + (size_t)(m0+row)*CE + sc*8;
      aco[i] = c*8;
    }
    u32x4 S0[8], S1[8], S2[8];           // TRIPLE reg sets: A(t) lives 3 steps

#define LOADA(T, RA) do{ \
  _Pragma("unroll") \
  for (int i=0;i<4;i++){ \
    asm volatile("global_load_dwordx4 %0, %2, off\n\tglobal_load_dwordx4 %1, %2, off offset:16" \
      : "=&v"((RA)[2*i]), "=&v"((RA)[2*i+1]) : "v"(aptr[i] + (size_t)(T)*64) : "memory"); \
  } \
}while(0)

#define STAGEB(T, SLOT) do{ \
  _Pragma("unroll") \
  for (int i=0;i<2;i++){ \
    int c = tid + i*512, row=c>>3, sc=(c&7)^(row&7); \
    __builtin_amdgcn_global_load_lds(GP(Wb + (size_t)(n0+row)*CE + (T)*64 + sc*8), \
                                     LP(&LDSU[32768 + (SLOT)*8192 + c*8]), 16, 0, 0); \
  } \
}while(0)

#define WRITEA(DST, RA) do{ \
  u16* _d = (DST); \
  _Pragma("unroll") \
  for (int i=0;i<4;i++){ \
    u32x4 w; CVTW(w, (RA)[2*i], (RA)[2*i+1]); \
    *(u32x4*)&_d[aco[i]] = w; \
  } \
}while(0)

// step T (0..12): stage B(T+2), issue A(T+3) into SL, wait WN (confirms through
// A(T+1), covering B(T)), flush A(T+1) from SW to LDS, compute tile T, barrier.
#define QSTEP(T, SL, SW, WN) do{ \
  STAGEB((T)+2, ((T)+2)&3); \
  LOADA((T)+3, SL); \
  WAITVM(WN); \
  WRITEA(((((T)+1)&1)?As1:As0), SW); \
  COMP((((T)&1)?As1:As0), &LDSU[32768 + ((T)&3)*8192]); \
  LGKMB; \
}while(0)

    // prologue: A0,B0,B1,A1,A2 in flight (28 loads); confirm A0 only (leave 20)
    LOADA(0, S0); STAGEB(0, 0); STAGEB(1, 1);
    LOADA(1, S1); LOADA(2, S2);
    WAITVM("20");
    WRITEA(As0, S0);
    LGKMB;

    QSTEP(0,  S0, S1, "18");   // A3->S0, flush A1
    QSTEP(1,  S1, S2, "20");   // A4->S1, flush A2
    QSTEP(2,  S2, S0, "20");
    QSTEP(3,  S0, S1, "20");
    QSTEP(4,  S1, S2, "20");
    QSTEP(5,  S2, S0, "20");
    QSTEP(6,  S0, S1, "20");
    QSTEP(7,  S1, S2, "20");
    QSTEP(8,  S2, S0, "20");
    QSTEP(9,  S0, S1, "20");
    QSTEP(10, S1, S2, "20");
    QSTEP(11, S2, S0, "20");
    QSTEP(12, S0, S1, "20");   // A15->S0, flush A13
    // t=13: stage B15 only; confirm through A14 (covers B13); flush A14
    STAGEB(15, 3);
    WAITVM("12");
    WRITEA(As0, S2);           // A14 -> As[14&1]=As0
    COMP(As1, &LDSU[32768 + 1*8192]);   // tile 13, slot 1
    LGKMB;
    // t=14: confirm through A15 (covers B14); flush A15
    WAITVM("2");
    WRITEA(As1, S0);           // A15 -> As[15&1]=As1
    COMP(As0, &LDSU[32768 + 2*8192]);   // tile 14, slot 2
    LGKMB;
    // t=15
    WAITVM("0");
    COMP(As1, &LDSU[32768 + 3*8192]);   // tile 15, slot 3

#undef LOADA
#undef STAGEB
#undef WRITEA
#undef QSTEP

    // ---- epilogue: bias + scale + RoPE + pack [B,H,L,D]
    const int colbase = n0 + wc*64;
    const float* bias = z ? bk : bq;
    u16* outp = z ? Kp : Qp;
    const float scale = z ? 1.f : 0.125f*LOG2E;
    const int h = colbase >> 6;           // wave covers exactly one head
    float b1[2], b2[2], invr[2];
    #pragma unroll
    for (int nr=0;nr<2;nr++){
      int j2 = nr*16 + llo;
      b1[nr] = bias[colbase + j2];
      b2[nr] = bias[colbase + j2 + 32];
      invr[nr] = exp2f(-(float)j2 * 0.41524101186092033f) * INV2PI;  // 10000^{-j2/32}/(2pi)
    }
    #pragma unroll
    for (int mr=0;mr<4;mr++)
      #pragma unroll
      for (int r=0;r<4;r++){
        int row = m0 + wr*64 + mr*16 + lhi*4 + r;
        int b = row >> 11, l = row & 2047;
        u16* dst = outp + (((size_t)(b*CH + h)*CL + l) << 6);
        #pragma unroll
        for (int nr=0;nr<2;nr++){
          int j2 = nr*16 + llo;
          float x1 = (acc[mr][nr][r]   + b1[nr]) * scale;
          float x2 = (acc[mr][nr+2][r] + b2[nr]) * scale;
          float fr = fractf_((float)l * invr[nr]);
          float sn = sinrev(fr), cs = cosrev(fr);
          dst[j2]      = f2bf(x1*cs - x2*sn);
          dst[j2 + 32] = f2bf(x2*cs + x1*sn);
        }
      }
  } else {
    // z==2: A = wvb bf16 gload_lds ring-3 (slots 0..2 at s*16384),
    //       B = value fp32 reg-staged, TRIPLE sets R0/R1/R2, dbuf Bs0/Bs1.
    u16* Bs0 = &LDSU[49152];
    u16* Bs1 = &LDSU[57344];

    const float* bptr[2]; int bco[2];
    #pragma unroll
    for (int i=0;i<2;i++){
      int c = tid + i*512, row=c>>3, sc=(c&7)^(row&7);
      bptr[i] = value + (size_t)(n0+row)*CE + sc*8;
      bco[i] = c*8;
    }
    u32x4 R0[4], R1[4], R2[4];

#define STAGEA(T, SLOT) do{ \
  _Pragma("unroll") \
  for (int i=0;i<4;i++){ \
    int c = tid + i*512, row=c>>3, sc=(c&7)^(row&7); \
    __builtin_amdgcn_global_load_lds(GP(wvb + (size_t)(m0+row)*CE + (T)*64 + sc*8), \
                                     LP(&LDSU[(SLOT)*16384 + c*8]), 16, 0, 0); \
  } \
}while(0)

#define LOADB(T, RB) do{ \
  _Pragma("unroll") \
  for (int i=0;i<2;i++){ \
    asm volatile("global_load_dwordx4 %0, %2, off\n\tglobal_load_dwordx4 %1, %2, off offset:16" \
      : "=&v"((RB)[2*i]), "=&v"((RB)[2*i+1]) : "v"(bptr[i] + (size_t)(T)*64) : "memory"); \
  } \
}while(0)

#define WRITEB(DST, RB) do{ \
  u16* _d = (DST); \
  _Pragma("unroll") \
  for (int i=0;i<2;i++){ \
    u32x4 w; CVTW(w, (RB)[2*i], (RB)[2*i+1]); \
    *(u32x4*)&_d[bco[i]] = w; \
  } \
}while(0)

// step T (0..12): stage A(T+2), issue B(T+3) into SL, wait WN (confirms through
// B(T+1), covering A(T)), flush B(T+1) from SW, compute tile T, barrier.
#define VSTEP(T, SL, SW, WN) do{ \
  STAGEA((T)+2, ((T)+2)%3); \
  LOADB((T)+3, SL); \
  WAITVM(WN); \
  WRITEB(((((T)+1)&1)?Bs1:Bs0), SW); \
  COMP(&LDSU[(((T))%3)*16384], (((T)&1)?Bs1:Bs0)); \
  LGKMB; \
}while(0)

    // prologue: A0,B0,A1,B1,B2 in flight (20 loads); confirm through B0 (leave 12)
    STAGEA(0,0); LOADB(0, R0);
    STAGEA(1,1); LOADB(1, R1);
    LOADB(2, R2);
    WAITVM("12");
    WRITEB(Bs0, R0);
    LGKMB;

    VSTEP(0,  R0, R1, "12");   // B3->R0, flush B1
    VSTEP(1,  R1, R2, "16");   // B4->R1, flush B2
    VSTEP(2,  R2, R0, "16");
    VSTEP(3,  R0, R1, "16");
    VSTEP(4,  R1, R2, "16");
    VSTEP(5,  R2, R0, "16");
    VSTEP(6,  R0, R1, "16");
    VSTEP(7,  R1, R2, "16");
    VSTEP(8,  R2, R0, "16");
    VSTEP(9,  R0, R1, "16");
    VSTEP(10, R1, R2, "16");
    VSTEP(11, R2, R0, "16");
    VSTEP(12, R0, R1, "16");   // B15->R0, flush B13
    // t=13: stage A15 only; confirm through B14 (covers A13); flush B14
    STAGEA(15, 0);
    WAITVM("12");
    WRITEB(Bs0, R2);           // B14 -> Bs[14&1]=Bs0
    COMP(&LDSU[1*16384], Bs1); // tile 13: A slot 13%3=1, Bs[13&1]=Bs1
    LGKMB;
    // t=14: confirm through B15 (covers A14); flush B15
    WAITVM("4");
    WRITEB(Bs1, R0);           // B15 -> Bs[15&1]=Bs1
    COMP(&LDSU[2*16384], Bs0); // tile 14: A slot 2, Bs0
    LGKMB;
    // t=15
    WAITVM("0");
    COMP(&LDSU[0*16384], Bs1); // tile 15: A slot 0, Bs1

#undef STAGEA
#undef LOADB
#undef WRITEB
#undef VSTEP

    // ---- epilogue: bias per row, write Vt [E][CM]
    const int colbase = n0 + wc*64;
    #pragma unroll
    for (int mr=0;mr<4;mr++)
      #pragma unroll
      for (int r=0;r<4;r++){
        int row = m0 + wr*64 + mr*16 + lhi*4 + r;
        float bvv = bv[row];
        #pragma unroll
        for (int nr=0;nr<4;nr++){
          int col = colbase + nr*16 + llo;
          Vt[(size_t)row*CM + col] = f2bf(acc[mr][nr][r] + bvv);
        }
      }
  }
}

// ---------------- output projection GEMM (fp32 out, bias per col) ----------------
// A = AO bf16 via global_load_lds ring-3; B = wo fp32 reg-staged (cast in staging).
__global__ __launch_bounds__(512) void gemm_out(
    const u16* __restrict__ A, const float* __restrict__ Btf,
    const float* __restrict__ bias, float* __restrict__ C)
{
  __shared__ u16 As[3][16384];   // 48KB
  __shared__ u16 Bs[2][8192];    // 32KB
  const int tid=threadIdx.x, lane=tid&63, wid=tid>>6;
  const int llo=lane&15, lhi=lane>>4;
  int bid = blockIdx.x;
  int xcd = bid&7, j = bid>>3;
  const int m0 = (xcd*4 + (j>>3))*256, n0 = (j&7)*128;   // 32 x 8 tiles of 256x128
  const int wr = wid>>1, wc = wid&1;
  const int rswA = llo&7;

  auto STAGEA = [&](int t, int buf){     // 4 gload_lds / thread
    #pragma unroll
    for (int i=0;i<4;i++){
      int c = tid + i*512, row=c>>3, sc=(c&7)^(row&7);
      __builtin_amdgcn_global_load_lds(GP(A + (size_t)(m0+row)*CE + t*64 + sc*8),
                                       LP(&As[buf][c*8]), 16, 0, 0);
    }
  };

  const float* bptr[2]; int bco[2];
  #pragma unroll
  for (int i=0;i<2;i++){
    int c = tid + i*512, row=c>>3, sc=(c&7)^(row&7);
    bptr[i] = Btf + (size_t)(n0+row)*CE + sc*8;
    bco[i] = c*8;
  }
  u32x4 B0[4], B1[4];

#define LOADB(T, RB) do{ \
  _Pragma("unroll") \
  for (int i=0;i<2;i++){ \
    asm volatile("global_load_dwordx4 %0, %2, off\n\tglobal_load_dwordx4 %1, %2, off offset:16" \
      : "=&v"((RB)[2*i]), "=&v"((RB)[2*i+1]) : "v"(bptr[i] + (size_t)(T)*64) : "memory"); \
  } \
}while(0)

#define WRITEB(BUF, RB) do{ \
  _Pragma("unroll") \
  for (int i=0;i<2;i++){ \
    u32x4 w; CVTW(w, (RB)[2*i], (RB)[2*i+1]); \
    *(u32x4*)&Bs[BUF][bco[i]] = w; \
  } \
}while(0)

  f32x4 acc[4][4] = {};

  auto COMP = [&](int abuf, int bbuf){
    const char* as = (const char*)As[abuf];
    const char* bs = (const char*)Bs[bbuf];
    #pragma unroll
    for (int ks=0; ks<2; ks++){
      bf16x8 af[4], bf_[4];
      #pragma unroll
      for (int mr=0;mr<4;mr++){
        int r = wr*64+mr*16+llo;
        af[mr] = as_bf(*(const uint4*)(as + r*128 + (((ks*4+lhi)^rswA)<<4)));
      }
      #pragma unroll
      for (int nr=0;nr<4;nr++){
        int r = wc*64+nr*16+llo;
        bf_[nr] = as_bf(*(const uint4*)(bs + r*128 + (((ks*4+lhi)^rswA)<<4)));
      }
      #pragma unroll
      for (int mr=0;mr<4;mr++)
        #pragma unroll
        for (int nr=0;nr<4;nr++)
          acc[mr][nr] = __builtin_amdgcn_mfma_f32_16x16x32_bf16(af[mr], bf_[nr], acc[mr][nr], 0,0,0);
    }
  };

  // prologue: A(0),B(0),A(1),B(1) in flight; confirm tile0 pair, write B0
  STAGEA(0,0); LOADB(0, B0);
  STAGEA(1,1); LOADB(1, B1);
  WAITVM("8");
  WRITEB(0, B0);
  LGKMB;

  #pragma unroll 1
  for (int jj=0; jj<7; jj++){
    const int t = 2*jj;
    STAGEA(t+2, (t+2)%3); LOADB(t+2, B0);
    WAITVM("8");
    WRITEB(1, B1);
    COMP(t%3, 0);
    LGKMB;
    STAGEA(t+3, (t+3)%3); LOADB(t+3, B1);
    WAITVM("8");
    WRITEB(0, B0);
    COMP((t+1)%3, 1);
    LGKMB;
  }
  WAITVM("0");
  WRITEB(1, B1);
  COMP(2, 0);          // t=14
  LGKMB;
  COMP(0, 1);          // t=15

#undef LOADB
#undef WRITEB

  #pragma unroll
  for (int mr=0;mr<4;mr++)
    #pragma unroll
    for (int nr=0;nr<4;nr++)
      #pragma unroll
      for (int r=0;r<4;r++){
        int row = m0 + wr*64 + mr*16 + lhi*4 + r;
        int col = n0 + wc*64 + nr*16 + llo;
        C[(size_t)row*CE + col] = acc[mr][nr][r] + bias[col];
      }
}

// ---------------- flash attention, T15 software pipeline ----------------
// Qp,Kp: [B*H, L, D] bf16 (Q pre-scaled by 0.125*log2e). Vt: [E, CM] bf16. Out AO [B,L,E] bf16.
__global__ __launch_bounds__(256,2) void attn_kernel(
    const u16* __restrict__ Qp, const u16* __restrict__ Kp, const u16* __restrict__ Vt,
    const float* __restrict__ maskf, u16* __restrict__ AO)
{
  __shared__ u16 K_lds[4][4096];   // ring of [kv64][d64] swizzled tiles
  __shared__ u16 V_lds[4][4096];   // ring of [d64][kv64] swizzled tiles
  __shared__ float M_lds[2048];    // padding mask row (exp2 domain) for this batch
  const int bh = blockIdx.x;
  const int slot = blockIdx.y;
  const int b = bh >> 4, h = bh & 15;
  const int tid=threadIdx.x, lane=tid&63, wid=tid>>6;
  const int l31 = lane&31, hi = lane>>5;
  const u16* Qh = Qp + (size_t)bh*CL*CD;
  const u16* Kh = Kp + (size_t)bh*CL*CD;
  const u16* Vhd = Vt + (size_t)(h*CD)*CM + b*CL;

  // stage padding-mask row once (8KB); confirmed by the first WAITB.
  #pragma unroll
  for (int i=0;i<2;i++)
    __builtin_amdgcn_global_load_lds(GP(maskf + b*CL + (i*256+tid)*4),
                                     LP(&M_lds[(i*256+tid)*4]), 16, 0, 0);

  auto STAGE = [&](int t, int buf){   // 4 gload_lds instructions per wave
    const u16* Ksrc = Kh + t*64*CD;
    const u16* Vsrc = Vhd + t*64;
    #pragma unroll
    for (int i=0;i<2;i++){
      int c = tid + i*256;
      int row = c>>3, sc = c&7;
      int c16 = sc ^ (row&7);
      __builtin_amdgcn_global_load_lds(GP(Ksrc + row*CD + c16*8),
                                       LP(&K_lds[buf][c*8]), 16, 0, 0);
      __builtin_amdgcn_global_load_lds(GP(Vsrc + (size_t)row*CM + c16*8),
                                       LP(&V_lds[buf][c*8]), 16, 0, 0);
    }
  };

  const int rowb = l31*128;            // LDS row byte base
  const int rsw  = (l31&7)<<4;
  const int qts2[2] = {15-slot, slot};

  for (int qi=0; qi<2; qi++){
    const int qt = qts2[qi];
    const int qw0 = qt*128 + wid*32;
    const int qlane = qw0 + l31;

    bf16x8 qf[4];
    #pragma unroll
    for (int c=0;c<4;c++)
      qf[c] = as_bf(*(const uint4*)(Qh + (size_t)qlane*CD + c*16 + hi*8));

    f32x16 o0 = {}, o1 = {};
    float m_r = -3e38f, l_r = 0.f;
    f32x16 sA0, sA1, sB0, sB1;         // double-banked S tiles

    const int nt = qt*2 + 2;
    STAGE(0,0); STAGE(1,1);

    // QK^T for tile t -> (d0,d1); Q carries 0.125*log2e
    auto QK = [&](int t, f32x16& d0, f32x16& d1){
      const char* kb = (const char*)K_lds[t&3];
      f32x16 z0 = {}, z1 = {};
      __builtin_amdgcn_s_setprio(1);
      #pragma unroll
      for (int c=0;c<4;c++){
        int cb = (c*32 + hi*16) ^ rsw;
        bf16x8 k0 = as_bf(*(const uint4*)(kb + rowb + cb));
        bf16x8 k1 = as_bf(*(const uint4*)(kb + 4096 + rowb + cb));
        z0 = __builtin_amdgcn_mfma_f32_32x32x16_bf16(k0, qf[c], z0, 0,0,0);
        z1 = __builtin_amdgcn_mfma_f32_32x32x16_bf16(k1, qf[c], z1, 0,0,0);
      }
      __builtin_amdgcn_s_setprio(0);
      d0 = z0; d1 = z1;
    };

    // softmax + PV for tile tp (S banks passed by ref; runs while QK(tp+1) drains)
    auto SMPV = [&](int tp, f32x16& s0, f32x16& s1){
      const int kv0 = tp*64;
      const char* vb = (const char*)V_lds[tp&3];

      // padding mask (broadcast LDS reads)
      f32x4 cm[8];
      #pragma unroll
      for (int s2=0;s2<2;s2++)
        #pragma unroll
        for (int g=0; g<4; g++)
          cm[s2*4+g] = *(const f32x4*)&M_lds[kv0 + s2*32 + g*8 + hi*4];

      // mask (+ causal on diagonal tiles), in place (exp2 domain)
      if (kv0 + 63 > qw0){
        #pragma unroll
        for (int s2=0;s2<2;s2++){
          f32x16& sv = s2 ? s1 : s0;
          #pragma unroll
          for (int reg=0; reg<16; reg++){
            int k = kv0 + s2*32 + (reg&3) + (reg>>2)*8 + hi*4;
            float v = sv[reg] + cm[s2*4+(reg>>2)][reg&3];
            sv[reg] = (k > qlane) ? v + NEGBIG : v;
          }
        }
      } else {
        #pragma unroll
        for (int s2=0;s2<2;s2++){
          f32x16& sv = s2 ? s1 : s0;
          #pragma unroll
          for (int reg=0; reg<16; reg++)
            sv[reg] = sv[reg] + cm[s2*4+(reg>>2)][reg&3];
        }
      }

      // row max
      f32x16 mx;
      #pragma unroll
      for (int r=0;r<16;r++) mx[r] = fmaxf(s0[r], s1[r]);
      float a0 = max3f(mx[0],mx[1],mx[2]);
      float a1 = max3f(mx[3],mx[4],mx[5]);
      float a2 = max3f(mx[6],mx[7],mx[8]);
      float a3 = max3f(mx[9],mx[10],mx[11]);
      float a4 = max3f(mx[12],mx[13],mx[14]);
      float vmax = fmaxf(max3f(a0,a1,a2), max3f(a3,a4,mx[15]));
      vmax = fmaxf(vmax, __shfl_xor(vmax, 32));

      // defer-max (T13)
      if (__any(vmax > m_r + 12.0f)){
        float mnew = fmaxf(m_r, vmax);
        float sc = fexp2(m_r - mnew);
        l_r *= sc;
        o0 *= sc; o1 *= sc;
        m_r = mnew;
      }

      // p = exp2(v - m)
      #pragma unroll
      for (int r=0;r<16;r++){
        s0[r] = fexp2(s0[r] - m_r);
        s1[r] = fexp2(s1[r] - m_r);
      }
      // row sum
      f32x16 sm = s0 + s1;
      #pragma unroll
      for (int w=8; w>=1; w>>=1)
        #pragma unroll
        for (int r=0;r<w;r++) sm[r] = sm[r] + sm[r+w];
      float rsum = sm[0];
      rsum += __shfl_xor(rsum, 32);
      l_r += rsum;

      // P -> bf16 B-fragments in-register
      u32 w_[16];
      #pragma unroll
      for (int s2=0;s2<2;s2++){
        f32x16& sv = s2 ? s1 : s0;
        #pragma unroll
        for (int c=0;c<2;c++){
          u32 a  = cvt_pk(sv[c*8+0], sv[c*8+1]);
          u32 bb = cvt_pk(sv[c*8+2], sv[c*8+3]);
          u32 cc = cvt_pk(sv[c*8+4], sv[c*8+5]);
          u32 dd = cvt_pk(sv[c*8+6], sv[c*8+7]);
          plswap(a, cc); plswap(bb, dd);
          int base = (s2*2+c)*4;
          w_[base+0]=a; w_[base+1]=bb; w_[base+2]=cc; w_[base+3]=dd;
        }
      }

      // O^T += V^T @ P^T
      __builtin_amdgcn_s_setprio(1);
      #pragma unroll
      for (int kc=0; kc<4; kc++){
        bf16x8 pf = as_bf(make_uint4(w_[kc*4], w_[kc*4+1], w_[kc*4+2], w_[kc*4+3]));
        int cb = (kc*32 + hi*16) ^ rsw;
        bf16x8 v0 = as_bf(*(const uint4*)(vb + rowb + cb));
        bf16x8 v1 = as_bf(*(const uint4*)(vb + 4096 + rowb + cb));
        o0 = __builtin_amdgcn_mfma_f32_32x32x16_bf16(v0, pf, o0, 0,0,0);
        o1 = __builtin_amdgcn_mfma_f32_32x32x16_bf16(v1, pf, o1, 0,0,0);
      }
      __builtin_amdgcn_s_setprio(0);
    };

    // t=0: QK only
    WAITB("4");                          // confirms S(0) (+mask, +qf)
    if (2 < nt) STAGE(2,2);
    QK(0, sA0, sA1);

    // pairs t=(2j+1, 2j+2), static S-bank parity
    #pragma unroll 1
    for (int jx=0; jx<qt; jx++){
      int t = 2*jx+1;                    // odd -> bank B
      WAITB("4");
      if (t+2 < nt) STAGE(t+2,(t+2)&3);
      QK(t, sB0, sB1);
      SMPV(t-1, sA0, sA1);
      t = 2*jx+2;                        // even -> bank A (never the last tile)
      WAITB("4");
      if (t+2 < nt) STAGE(t+2,(t+2)&3);
      QK(t, sA0, sA1);
      SMPV(t-1, sB0, sB1);
    }
    // t = nt-1 (odd)
    WAITB("0");
    QK(nt-1, sB0, sB1);
    SMPV(nt-2, sA0, sA1);
    // finish last tile
    SMPV(nt-1, sB0, sB1);

    // normalize + write O^T: lane has q=qlane, d = mt*32 + g*8 + hi*4 + {0..3}
    float inv = 1.f / l_r;
    u16* dst = AO + (size_t)(b*CL + qlane)*CE + h*CD;
    #pragma unroll
    for (int mt=0; mt<2; mt++){
      f32x16& ov = mt ? o1 : o0;
      #pragma unroll
      for (int g=0; g<4; g++){
        u32 lo  = cvt_pk(ov[g*4+0]*inv, ov[g*4+1]*inv);
        u32 hi2 = cvt_pk(ov[g*4+2]*inv, ov[g*4+3]*inv);
        *(uint2*)(dst + mt*32 + g*8 + hi*4) = make_uint2(lo, hi2);
      }
    }
    // protect ring reuse by qi=1 prologue (and reset vmcnt ledger)
    __syncthreads();
  }
}

// ---------------- launcher ----------------
extern "C" void kernel_launch(void* const* d_in, const int* in_sizes, int n_in,
                              void* d_out, int out_size, void* d_ws, size_t ws_size,
                              hipStream_t stream) {
  const float* query = (const float*)d_in[0];
  const float* key_  = (const float*)d_in[1];
  const float* value = (const float*)d_in[2];
  const float* wq = (const float*)d_in[3];
  const float* bq = (const float*)d_in[4];
  const float* wk = (const float*)d_in[5];
  const float* bk = (const float*)d_in[6];
  const float* wv = (const float*)d_in[7];
  const float* bv = (const float*)d_in[8];
  const float* wo = (const float*)d_in[9];
  const float* bo = (const float*)d_in[10];
  const void*  kpm = d_in[11];

  char* ws = (char*)d_ws;
  constexpr size_t SZ_ME_BF = (size_t)CM*CE*2;    // 16 MiB
  constexpr size_t OFF_MASKF= 256;
  constexpr size_t OFF_AO   = 65536;              // attn output, bf16 [B,L,E]
  constexpr size_t OFF_KP   = OFF_AO + SZ_ME_BF;
  constexpr size_t OFF_VT   = OFF_KP + SZ_ME_BF;  // Vt [1024][8192]
  constexpr size_t OFF_QP   = OFF_VT + SZ_ME_BF;

  float* maskf = (float*)(ws + OFF_MASKF);
  u16*  AO  = (u16*)(ws + OFF_AO);
  u16*  Kp  = (u16*)(ws + OFF_KP);
  u16*  Vt  = (u16*)(ws + OFF_VT);
  u16*  Qp  = (u16*)(ws + OFF_QP);

  // bf16 weights live in the head of AO: dead until attn writes AO (stream-ordered,
  // gemm_qkv completes before attn starts). 3 x 1M u16 = 6MB < 16MB.
  u16* wqb = AO;
  u16* wkb = AO + (size_t)CE*CE;
  u16* wvb = AO + (size_t)2*CE*CE;

  prep_kernel<<<3104,256,0,stream>>>(wq, wk, wv, wqb, wkb, wvb, kpm, maskf);

  gemm_qkv<<<dim3(256,3),512,0,stream>>>(query, key_, value, wqb, wkb, wvb,
                                         bq, bk, bv, Qp, Kp, Vt);

  attn_kernel<<<dim3(CB*CH, 8),256,0,stream>>>(Qp, Kp, Vt, maskf, AO);

  gemm_out<<<256,512,0,stream>>>(AO, wo, bo, (float*)d_out);
}